// Round 1
// 212.962 us; speedup vs baseline: 1.0186x; 1.0186x over previous
//
#include <hip/hip_runtime.h>
#include <hip/hip_bf16.h>

#define BB 4
#define LL 2048
#define DM 1024
#define NH 16
#define FEAT 16
#define HD 64
#define CHUNK 128
#define NCHUNK 16
#define NEXT 80               // 64 v-cols + 1 ones-col + 15 pad
#define SROW 23040            // 18 dtiles x 80 e x 16 d = per-(bh,c) slab elems
#define EPS 1e-12f
#define INV_R2RD 0.17677669529663688f   // 1/(4*sqrt(2))
#define QKVLD 1536

typedef short bf16x8_t __attribute__((ext_vector_type(8)));
typedef float f32x4_t  __attribute__((ext_vector_type(4)));

__device__ __forceinline__ float b2f(unsigned short u) {
    union { unsigned int i; float f; } x; x.i = ((unsigned int)u) << 16; return x.f;
}
__device__ __forceinline__ unsigned short f2b(float f) {
    __hip_bfloat16 h = __float2bfloat16(f);
    return *reinterpret_cast<unsigned short*>(&h);
}

// ---------------------------------------------------------------------------
// One kernel for all fp32->bf16 casts (5 segments, compile-time boundaries).
// ---------------------------------------------------------------------------
__global__ __launch_bounds__(256)
void cast_all(const float* __restrict__ hs, const float* __restrict__ wq,
              const float* __restrict__ wk, const float* __restrict__ wv,
              const float* __restrict__ wo, unsigned short* __restrict__ hs_bf,
              unsigned short* __restrict__ wqkv, unsigned short* __restrict__ wo_bf)
{
    const int i = (blockIdx.x * 256 + threadIdx.x) * 4;
    const float* s; unsigned short* d;
    if (i < 8388608)       { s = hs + i;             d = hs_bf + i; }
    else if (i < 8650752)  { s = wq + (i - 8388608); d = wqkv + (i - 8388608); }
    else if (i < 8912896)  { s = wk + (i - 8650752); d = wqkv + 262144 + (i - 8650752); }
    else if (i < 9961472)  { s = wv + (i - 8912896); d = wqkv + 524288 + (i - 8912896); }
    else if (i < 11010048) { s = wo + (i - 9961472); d = wo_bf + (i - 9961472); }
    else return;
    float4 v = *(const float4*)s;
    ushort4 o; o.x = f2b(v.x); o.y = f2b(v.y); o.z = f2b(v.z); o.w = f2b(v.w);
    *(ushort4*)d = o;
}

// ---------------------------------------------------------------------------
// bf16 MFMA GEMM, 256x256 tile, BK=64, 8-phase counted-vmcnt schedule
// (m201 template: T2 XOR-swizzle + T3/T4 counted vmcnt + T5 setprio).
// C[M,N] = A[M,K] @ Bw[N,K]^T, fp32 acc. 512 threads = 8 waves (2M x 4N),
// per-wave output 128x64 (m-frags interleaved by wave: row=(2m+wm)*16,
// col=(4n+wn)*16 so A-half0 = tile rows 0..127 for both m-waves).
// LDS 128 KiB: A[2 dbuf][256][64] @0, B[2 dbuf][256][64] @32768 (ushort).
// Swizzle: lds[row][c ^ ((row&7)<<3)] holds A[row][c]; staging keeps the
// LDS dest linear (global_load_lds requirement) and pre-swizzles the
// per-lane GLOBAL column instead (rule 21). Staging schedule per tile t:
//   p0:(t+1,B,h1)  p1:(t+2,A,h0)  p2:(t+2,B,h0)  p3:(t+2,A,h1)
// boundary s_waitcnt vmcnt(6) => next tile's 4 half-tiles landed, 3 in
// flight. Epilogue drain: vmcnt(0) at t==NT-2, nothing at t==NT-1.
// ---------------------------------------------------------------------------
template <typename OutT>
__global__ __launch_bounds__(512, 2)
void gemm_bf16_8ph(const unsigned short* __restrict__ A, const unsigned short* __restrict__ Bw,
                   OutT* __restrict__ C, int K, int lda, int ldb, int ldc)
{
    __shared__ unsigned short lds[65536];   // 128 KiB
    const int tid  = threadIdx.x;
    const int wid  = tid >> 6, lane = tid & 63;
    const int wm   = wid >> 2, wn = wid & 3;
    const int ml   = lane & 15, quad = lane >> 4;
    const int m0   = blockIdx.y * 256, n0 = blockIdx.x * 256;
    const int NT   = K >> 6;

    // staging geometry: thread covers 8 contiguous cols of one row;
    // LDS dest is wave-linear (base + lane*16B), global col pre-swizzled.
    const int srow  = tid >> 3;                       // 0..63 row within 64-row load block
    const int scol  = ((tid & 7) ^ (srow & 7)) << 3;  // pre-swizzled col (elems)
    const int wbase = wid << 9;                       // wid*8 rows * 64 elems

    auto stage_half = [&](int t, int isB, int h) {
        const unsigned short* g0 = isB ? Bw : A;
        const int ld = isB ? ldb : lda;
        const int rb = (isB ? n0 : m0) + h * 128 + srow;
        const int k0 = t << 6;
        unsigned short* lb = lds + (isB ? 32768 : 0) + ((t & 1) << 14) + (h << 13) + wbase;
#pragma unroll
        for (int l = 0; l < 2; ++l) {
            const unsigned short* g = g0 + (size_t)(rb + l * 64) * ld + k0 + scol;
            __builtin_amdgcn_global_load_lds((const __attribute__((address_space(1))) void*)g,
                                             (__attribute__((address_space(3))) void*)(lb + l * 4096),
                                             16, 0, 0);
        }
    };

    f32x4_t acc[8][4];
#pragma unroll
    for (int i = 0; i < 8; ++i)
#pragma unroll
        for (int j = 0; j < 4; ++j) acc[i][j] = (f32x4_t){0.f, 0.f, 0.f, 0.f};

    // prologue: tile0 fully + tile1 {A0,B0,A1}; oldest 8 loads = tile0.
    stage_half(0, 0, 0); stage_half(0, 1, 0); stage_half(0, 0, 1); stage_half(0, 1, 1);
    stage_half(1, 0, 0); stage_half(1, 1, 0); stage_half(1, 0, 1);
    asm volatile("s_waitcnt vmcnt(6)" ::: "memory");
    __builtin_amdgcn_s_barrier();

    const int swz  = (ml & 7) << 3;
    const int c0   = (quad << 3) ^ swz;          // ks=0 frag col, swizzled
    const int c1   = (32 + (quad << 3)) ^ swz;   // ks=1
    const int arow = ml << 6;                     // ml * 64

    bf16x8_t aA[4][2], bLo[2][2], bHi[2][2];

    for (int t = 0; t < NT; ++t) {
        const int ab = (t & 1) << 14;
        const int bb = 32768 + ((t & 1) << 14);

        // ---- phase 0: read A-h0 (m0..3) + B-h0 (n0..1); stage (t+1,B,h1) ----
#pragma unroll
        for (int m = 0; m < 4; ++m) {
            const int r = ab + ((2 * m + wm) << 10) + arow;
            aA[m][0] = *(const bf16x8_t*)&lds[r + c0];
            aA[m][1] = *(const bf16x8_t*)&lds[r + c1];
        }
#pragma unroll
        for (int n = 0; n < 2; ++n) {
            const int r = bb + ((4 * n + wn) << 10) + arow;
            bLo[n][0] = *(const bf16x8_t*)&lds[r + c0];
            bLo[n][1] = *(const bf16x8_t*)&lds[r + c1];
        }
        if (t + 1 < NT) stage_half(t + 1, 1, 1);
        __builtin_amdgcn_s_barrier();
        asm volatile("s_waitcnt lgkmcnt(0)" ::: "memory");
        __builtin_amdgcn_sched_barrier(0);
        __builtin_amdgcn_s_setprio(1);
#pragma unroll
        for (int m = 0; m < 4; ++m)
#pragma unroll
            for (int n = 0; n < 2; ++n) {
                acc[m][n] = __builtin_amdgcn_mfma_f32_16x16x32_bf16(aA[m][0], bLo[n][0], acc[m][n], 0, 0, 0);
                acc[m][n] = __builtin_amdgcn_mfma_f32_16x16x32_bf16(aA[m][1], bLo[n][1], acc[m][n], 0, 0, 0);
            }
        __builtin_amdgcn_s_setprio(0);
        __builtin_amdgcn_s_barrier();

        // ---- phase 1: read B-h1 (n2..3); stage (t+2,A,h0) ----
#pragma unroll
        for (int n = 0; n < 2; ++n) {
            const int r = bb + ((4 * (n + 2) + wn) << 10) + arow;
            bHi[n][0] = *(const bf16x8_t*)&lds[r + c0];
            bHi[n][1] = *(const bf16x8_t*)&lds[r + c1];
        }
        if (t + 2 < NT) stage_half(t + 2, 0, 0);
        __builtin_amdgcn_s_barrier();
        asm volatile("s_waitcnt lgkmcnt(0)" ::: "memory");
        __builtin_amdgcn_sched_barrier(0);
        __builtin_amdgcn_s_setprio(1);
#pragma unroll
        for (int m = 0; m < 4; ++m)
#pragma unroll
            for (int n = 0; n < 2; ++n) {
                acc[m][2 + n] = __builtin_amdgcn_mfma_f32_16x16x32_bf16(aA[m][0], bHi[n][0], acc[m][2 + n], 0, 0, 0);
                acc[m][2 + n] = __builtin_amdgcn_mfma_f32_16x16x32_bf16(aA[m][1], bHi[n][1], acc[m][2 + n], 0, 0, 0);
            }
        __builtin_amdgcn_s_setprio(0);
        __builtin_amdgcn_s_barrier();

        // ---- phase 2: read A-h1 (m4..7, reuses aA regs); stage (t+2,B,h0) ----
#pragma unroll
        for (int m = 0; m < 4; ++m) {
            const int r = ab + ((2 * (m + 4) + wm) << 10) + arow;
            aA[m][0] = *(const bf16x8_t*)&lds[r + c0];
            aA[m][1] = *(const bf16x8_t*)&lds[r + c1];
        }
        if (t + 2 < NT) stage_half(t + 2, 1, 0);
        __builtin_amdgcn_s_barrier();
        asm volatile("s_waitcnt lgkmcnt(0)" ::: "memory");
        __builtin_amdgcn_sched_barrier(0);
        __builtin_amdgcn_s_setprio(1);
#pragma unroll
        for (int m = 0; m < 4; ++m)
#pragma unroll
            for (int n = 0; n < 2; ++n) {
                acc[4 + m][2 + n] = __builtin_amdgcn_mfma_f32_16x16x32_bf16(aA[m][0], bHi[n][0], acc[4 + m][2 + n], 0, 0, 0);
                acc[4 + m][2 + n] = __builtin_amdgcn_mfma_f32_16x16x32_bf16(aA[m][1], bHi[n][1], acc[4 + m][2 + n], 0, 0, 0);
            }
        __builtin_amdgcn_s_setprio(0);
        __builtin_amdgcn_s_barrier();

        // ---- phase 3: no reads; stage (t+2,A,h1); boundary vmcnt ----
        if (t + 2 < NT) stage_half(t + 2, 0, 1);
        __builtin_amdgcn_s_barrier();
        asm volatile("s_waitcnt lgkmcnt(0)" ::: "memory");
        __builtin_amdgcn_sched_barrier(0);
        __builtin_amdgcn_s_setprio(1);
#pragma unroll
        for (int m = 0; m < 4; ++m)
#pragma unroll
            for (int n = 0; n < 2; ++n) {
                acc[4 + m][n] = __builtin_amdgcn_mfma_f32_16x16x32_bf16(aA[m][0], bLo[n][0], acc[4 + m][n], 0, 0, 0);
                acc[4 + m][n] = __builtin_amdgcn_mfma_f32_16x16x32_bf16(aA[m][1], bLo[n][1], acc[4 + m][n], 0, 0, 0);
            }
        __builtin_amdgcn_s_setprio(0);
        if (t + 2 < NT)      asm volatile("s_waitcnt vmcnt(6)" ::: "memory");
        else if (t + 1 < NT) asm volatile("s_waitcnt vmcnt(0)" ::: "memory");
        __builtin_amdgcn_s_barrier();
    }

    // ---- epilogue: C write ----
#pragma unroll
    for (int m = 0; m < 8; ++m) {
        const int rbase = m0 + (2 * m + wm) * 16 + quad * 4;
#pragma unroll
        for (int n = 0; n < 4; ++n) {
            const int col = n0 + (4 * n + wn) * 16 + ml;
#pragma unroll
            for (int r = 0; r < 4; ++r) {
                const float v = acc[m][n][r];
                if constexpr (sizeof(OutT) == 2) {
                    ((unsigned short*)C)[(size_t)(rbase + r) * ldc + col] = f2b(v);
                } else {
                    ((float*)C)[(size_t)(rbase + r) * ldc + col] = v;
                }
            }
        }
    }
}

// ---------------------------------------------------------------------------
// state_kernel: per (bh,c) computes S_c = Kf^T @ V_ext (MFMA), stored in the
// TILED layout: slab[dtile 0..17][e 0..79][dlocal 0..15], d = dtile*16+dlocal.
// Feature order d: [1][q/2 x16][0 x7][qxq/(4sqrt2) x256][0 x8]; e=64 -> z.
// ---------------------------------------------------------------------------
__global__ __launch_bounds__(256)
void state_kernel(const unsigned short* __restrict__ qkv, unsigned short* __restrict__ STg)
{
    __shared__ unsigned short KT[16 * 136];   // K transposed [f][j], padded
    __shared__ unsigned short VT[80 * 136];   // V_ext transposed [e][j], padded

    const int x = blockIdx.x;
    const int c = x & 15, bh = x >> 4;
    const int b = bh >> 4, h = bh & 15;
    const int tid = threadIdx.x;
    const int wave = tid >> 6, lane = tid & 63;
    const int ml = lane & 15, kg8 = (lane >> 4) * 8;
    const size_t rowbase = (size_t)(b * LL + c * CHUNK);
    const size_t Sbase = (size_t)x * SROW;

    {
        const int row = tid >> 1, half = tid & 1;
        uint4 kv = *(const uint4*)(qkv + (rowbase + row) * QKVLD + 256 + h * 16 + half * 8);
        const unsigned short* kp = (const unsigned short*)&kv;
#pragma unroll
        for (int i = 0; i < 8; ++i) KT[(half * 8 + i) * 136 + row] = kp[i];
#pragma unroll
        for (int cc = 0; cc < 4; ++cc) {
            uint4 vv = *(const uint4*)(qkv + (rowbase + row) * QKVLD + 512 + h * 64 + half * 32 + cc * 8);
            const unsigned short* vp = (const unsigned short*)&vv;
#pragma unroll
            for (int i = 0; i < 8; ++i) VT[(half * 32 + cc * 8 + i) * 136 + row] = vp[i];
        }
        if (half == 0) {
            VT[64 * 136 + row] = 0x3F80;   // ones column
        } else {
#pragma unroll
            for (int e = 65; e < 80; ++e) VT[e * 136 + row] = 0;
        }
    }
    __syncthreads();

    bf16x8_t bfr[5][4];
#pragma unroll
    for (int nt = 0; nt < 5; ++nt)
#pragma unroll
        for (int ks = 0; ks < 4; ++ks)
            bfr[nt][ks] = *(const bf16x8_t*)&VT[(nt * 16 + ml) * 136 + ks * 32 + kg8];

    for (int mt = wave; mt < 18; mt += 4) {
        const int d = mt * 16 + ml;
        bf16x8_t af[4];
#pragma unroll
        for (int ks = 0; ks < 4; ++ks) {
            const int jb = ks * 32 + kg8;
            unsigned short o[8];
            if (d >= 24 && d < 280) {
                const int e = d - 24, a = e >> 4, bq = e & 15;
                bf16x8_t ka = *(const bf16x8_t*)&KT[a  * 136 + jb];
                bf16x8_t kb = *(const bf16x8_t*)&KT[bq * 136 + jb];
#pragma unroll
                for (int j = 0; j < 8; ++j)
                    o[j] = f2b(b2f((unsigned short)ka[j]) * b2f((unsigned short)kb[j]) * INV_R2RD);
            } else if (d == 0) {
#pragma unroll
                for (int j = 0; j < 8; ++j) o[j] = 0x3F80;
            } else if (d <= 16) {
                bf16x8_t kx = *(const bf16x8_t*)&KT[(d - 1) * 136 + jb];
#pragma unroll
                for (int j = 0; j < 8; ++j) o[j] = f2b(b2f((unsigned short)kx[j]) * 0.5f);
            } else {
#pragma unroll
                for (int j = 0; j < 8; ++j) o[j] = 0;
            }
            af[ks] = *(const bf16x8_t*)o;
        }
        f32x4_t acc[5];
#pragma unroll
        for (int nt = 0; nt < 5; ++nt) acc[nt] = (f32x4_t){0.f, 0.f, 0.f, 0.f};
#pragma unroll
        for (int nt = 0; nt < 5; ++nt)
#pragma unroll
            for (int ks = 0; ks < 4; ++ks)
                acc[nt] = __builtin_amdgcn_mfma_f32_16x16x32_bf16(af[ks], bfr[nt][ks], acc[nt], 0, 0, 0);
        // tiled store: slab[mt][e = nt*16+ml][dlocal = quad*4 + r]
#pragma unroll
        for (int nt = 0; nt < 5; ++nt) {
            ushort4 pk;
            pk.x = f2b(acc[nt][0]); pk.y = f2b(acc[nt][1]);
            pk.z = f2b(acc[nt][2]); pk.w = f2b(acc[nt][3]);
            *(ushort4*)(STg + Sbase + (size_t)mt * 1280 + (nt * 16 + ml) * 16 + (lane >> 4) * 4) = pk;
        }
    }
}

// ---------------------------------------------------------------------------
// scan: exclusive prefix over the 16 chunks, elementwise, uint4 per thread.
// ---------------------------------------------------------------------------
__global__ __launch_bounds__(256)
void scan_S(unsigned short* __restrict__ STg) {
    const int bh  = blockIdx.y;
    const int idx = blockIdx.x * 256 + threadIdx.x;   // uint4 index, 0..2879
    if (idx >= SROW / 8) return;
    const size_t base = (size_t)bh * NCHUNK * SROW + (size_t)idx * 8;
    float acc[8] = {};
    for (int c = 0; c < NCHUNK; ++c) {
        unsigned short* p = STg + base + (size_t)c * SROW;
        uint4 v = *(const uint4*)p;
        const unsigned short* vp = (const unsigned short*)&v;
        uint4 o;
        unsigned short* op = (unsigned short*)&o;
#pragma unroll
        for (int i = 0; i < 8; ++i) { op[i] = f2b(acc[i]); acc[i] += b2f(vp[i]); }
        *(uint4*)p = o;
    }
}

// ---------------------------------------------------------------------------
// out_kernel: per (bh,c), 256 threads / 4 waves.
// Phase 1: A = poly(Q K^T / 4) masked (MFMA), A staged bf16 in LDS.
// Phase 2a: Y += A @ V_ext (MFMA, VT in LDS).
// Phase 2b: Y += Qf @ S_ext — BARRIER-FREE: B-fragments loaded directly
//   global->VGPR from the tiled ST slab, double-buffered (prefetch kq+1
//   during MFMA of kq; slice 0 issued at kernel top).
// LDS (ushort units): Qpad[128*40]@0 + Kpad[128*40]@5120 (VT[80*136]@0
// overlays both after phase 1) | A[128*136]@10880 | Qs[128*16]@28288.
// ---------------------------------------------------------------------------
#define OFF_VT 0
#define OFF_QP 0
#define OFF_KP 5120
#define OFF_A  10880
#define OFF_QS 28288

__global__ __launch_bounds__(256)
void out_kernel(const unsigned short* __restrict__ qkv_ro, const unsigned short* __restrict__ STg,
                unsigned short* __restrict__ qkv_w)
{
    __shared__ unsigned short smem[30336];   // 60672 B

    const int x = blockIdx.x;
    const int c = x & 15, bh = x >> 4;
    const int b = bh >> 4, h = bh & 15;
    const int tid = threadIdx.x;
    const int w = tid >> 6, lane = tid & 63;
    const int ml = lane & 15, quad = lane >> 4, kg8 = quad * 8;
    const size_t rowbase = (size_t)(b * LL + c * CHUNK);
    const size_t Sbase = (size_t)x * SROW;

    // ---- early prefetch of ST slice kq=0 (in flight through phase 1) ----
    const unsigned short* stp = STg + Sbase + (size_t)(quad >> 1) * 1280 + (quad & 1) * 8;
    bf16x8_t stf[2][5];
#pragma unroll
    for (int nt = 0; nt < 5; ++nt)
        stf[0][nt] = *(const bf16x8_t*)(stp + (nt * 16 + ml) * 16);

    // ---- load Q (padded + small) and K (padded) ----
    {
        const int row = tid >> 1, half = tid & 1;
        uint4 qv = *(const uint4*)(qkv_ro + (rowbase + row) * QKVLD + h * 16 + half * 8);
        *(uint4*)&smem[OFF_QP + row * 40 + half * 8] = qv;
        *(uint4*)&smem[OFF_QP + row * 40 + 16 + half * 8] = (uint4){0, 0, 0, 0};
        *(uint4*)&smem[OFF_QS + row * 16 + half * 8] = qv;
        uint4 kv = *(const uint4*)(qkv_ro + (rowbase + row) * QKVLD + 256 + h * 16 + half * 8);
        *(uint4*)&smem[OFF_KP + row * 40 + half * 8] = kv;
        *(uint4*)&smem[OFF_KP + row * 40 + 16 + half * 8] = (uint4){0, 0, 0, 0};
    }
    __syncthreads();

    // ---- phase 1: scores ----
    {
        bf16x8_t q0 = *(const bf16x8_t*)&smem[OFF_QP + (w * 32 + ml) * 40 + kg8];
        bf16x8_t q1 = *(const bf16x8_t*)&smem[OFF_QP + (w * 32 + 16 + ml) * 40 + kg8];
#pragma unroll
        for (int nt = 0; nt < 8; ++nt) {
            bf16x8_t kf = *(const bf16x8_t*)&smem[OFF_KP + (nt * 16 + ml) * 40 + kg8];
            f32x4_t a0 = __builtin_amdgcn_mfma_f32_16x16x32_bf16(q0, kf, (f32x4_t){0,0,0,0}, 0, 0, 0);
            f32x4_t a1 = __builtin_amdgcn_mfma_f32_16x16x32_bf16(q1, kf, (f32x4_t){0,0,0,0}, 0, 0, 0);
            const int j = nt * 16 + ml;
#pragma unroll
            for (int r = 0; r < 4; ++r) {
                int i0 = w * 32 + quad * 4 + r;
                float s0 = a0[r] * 0.25f;
                float v0 = (j <= i0) ? (1.f + s0 + 0.5f * s0 * s0) : 0.f;
                smem[OFF_A + i0 * 136 + j] = f2b(v0);
                int i1 = i0 + 16;
                float s1 = a1[r] * 0.25f;
                float v1 = (j <= i1) ? (1.f + s1 + 0.5f * s1 * s1) : 0.f;
                smem[OFF_A + i1 * 136 + j] = f2b(v1);
            }
        }
    }
    // q f32 registers for Qf build
    const int r0 = w * 32 + ml, r1 = r0 + 16;
    float qA[16], qB[16];
    {
        bf16x8_t t0 = *(const bf16x8_t*)&smem[OFF_QS + r0 * 16];
        bf16x8_t t1 = *(const bf16x8_t*)&smem[OFF_QS + r0 * 16 + 8];
        bf16x8_t t2 = *(const bf16x8_t*)&smem[OFF_QS + r1 * 16];
        bf16x8_t t3 = *(const bf16x8_t*)&smem[OFF_QS + r1 * 16 + 8];
#pragma unroll
        for (int i = 0; i < 8; ++i) {
            qA[i] = b2f((unsigned short)t0[i]); qA[8 + i] = b2f((unsigned short)t1[i]);
            qB[i] = b2f((unsigned short)t2[i]); qB[8 + i] = b2f((unsigned short)t3[i]);
        }
    }
    __syncthreads();   // A-writes + Qpad/Kpad reads done before VT overlay

    // ---- load VT (overlays Qpad/Kpad) ----
    {
        const int row = tid >> 1, half = tid & 1;
#pragma unroll
        for (int cc = 0; cc < 4; ++cc) {
            uint4 vv = *(const uint4*)(qkv_ro + (rowbase + row) * QKVLD + 512 + h * 64 + half * 32 + cc * 8);
            const unsigned short* vp = (const unsigned short*)&vv;
#pragma unroll
            for (int i = 0; i < 8; ++i) smem[OFF_VT + (half * 32 + cc * 8 + i) * 136 + row] = vp[i];
        }
        if (half == 0) {
            smem[OFF_VT + 64 * 136 + row] = 0x3F80;
        } else {
#pragma unroll
            for (int e = 65; e < 80; ++e) smem[OFF_VT + e * 136 + row] = 0;
        }
    }
    __syncthreads();

    f32x4_t acc[2][5];
#pragma unroll
    for (int mt = 0; mt < 2; ++mt)
#pragma unroll
        for (int nt = 0; nt < 5; ++nt) acc[mt][nt] = (f32x4_t){0.f, 0.f, 0.f, 0.f};

    // ---- phase 2a: A @ V_ext ----
#pragma unroll
    for (int ks = 0; ks < 4; ++ks) {
        bf16x8_t af0 = *(const bf16x8_t*)&smem[OFF_A + (w * 32 + ml) * 136 + ks * 32 + kg8];
        bf16x8_t af1 = *(const bf16x8_t*)&smem[OFF_A + (w * 32 + 16 + ml) * 136 + ks * 32 + kg8];
#pragma unroll
        for (int nt = 0; nt < 5; ++nt) {
            bf16x8_t bv = *(const bf16x8_t*)&smem[OFF_VT + (nt * 16 + ml) * 136 + ks * 32 + kg8];
            acc[0][nt] = __builtin_amdgcn_mfma_f32_16x16x32_bf16(af0, bv, acc[0][nt], 0, 0, 0);
            acc[1][nt] = __builtin_amdgcn_mfma_f32_16x16x32_bf16(af1, bv, acc[1][nt], 0, 0, 0);
        }
    }

    // ---- phase 2b: Qf @ S_ext, barrier-free, double-buffered global reads ----
#pragma unroll
    for (int kq = 0; kq < 9; ++kq) {
        if (kq < 8) {
#pragma unroll
            for (int nt = 0; nt < 5; ++nt)
                stf[(kq + 1) & 1][nt] =
                    *(const bf16x8_t*)(stp + (size_t)(kq + 1) * 2560 + (nt * 16 + ml) * 16);
        }
        bf16x8_t qf[2];
#pragma unroll
        for (int mt = 0; mt < 2; ++mt) {
            const float* q = (mt == 0) ? qA : qB;
            const int qsrow = (mt == 0) ? r0 : r1;
            const int d0 = kq * 32 + kg8;
            unsigned short o[8];
            if (d0 >= 24 && d0 < 280) {
                const int e0 = d0 - 24;
                const float qa = b2f(smem[OFF_QS + qsrow * 16 + (e0 >> 4)]) * INV_R2RD;
                if ((e0 & 15) == 0) {
#pragma unroll
                    for (int j = 0; j < 8; ++j) o[j] = f2b(qa * q[j]);
                } else {
#pragma unroll
                    for (int j = 0; j < 8; ++j) o[j] = f2b(qa * q[8 + j]);
                }
            } else if (d0 == 0) {
                o[0] = 0x3F80;
#pragma unroll
                for (int j = 1; j < 8; ++j) o[j] = f2b(q[j - 1] * 0.5f);
            } else if (d0 == 8) {
#pragma unroll
                for (int j = 0; j < 8; ++j) o[j] = f2b(q[7 + j] * 0.5f);
            } else if (d0 == 16) {
                o[0] = f2b(q[15] * 0.5f);
#pragma unroll
                for (int j = 1; j < 8; ++j) o[j] = 0;
            } else {
#pragma unroll
                for (int j = 0; j < 8; ++j) o[j] = 0;
            }
            qf[mt] = *(const bf16x8_t*)o;
        }
#pragma unroll
        for (int nt = 0; nt < 5; ++nt) {
            acc[0][nt] = __builtin_amdgcn_mfma_f32_16x16x32_bf16(qf[0], stf[kq & 1][nt], acc[0][nt], 0, 0, 0);
            acc[1][nt] = __builtin_amdgcn_mfma_f32_16x16x32_bf16(qf[1], stf[kq & 1][nt], acc[1][nt], 0, 0, 0);
        }
    }

    // ---- epilogue: y = num / (den + eps), den = col 64 (nt=4, ml==0 lanes) ----
#pragma unroll
    for (int mt = 0; mt < 2; ++mt) {
        float den[4];
#pragma unroll
        for (int r = 0; r < 4; ++r) den[r] = __shfl(acc[mt][4][r], lane & 48);
#pragma unroll
        for (int r = 0; r < 4; ++r) {
            const size_t grow = rowbase + w * 32 + mt * 16 + quad * 4 + r;
            const float rc = 1.f / (den[r] + EPS);
#pragma unroll
            for (int nt = 0; nt < 4; ++nt)
                qkv_w[grow * QKVLD + 512 + h * 64 + nt * 16 + ml] = f2b(acc[mt][nt][r] * rc);
        }
    }
}

// ---------------------------------------------------------------------------
extern "C" void kernel_launch(void* const* d_in, const int* in_sizes, int n_in,
                              void* d_out, int out_size, void* d_ws, size_t ws_size,
                              hipStream_t stream)
{
    (void)in_sizes; (void)n_in; (void)out_size; (void)ws_size;
    const float* hs = (const float*)d_in[0];
    const float* Wq = (const float*)d_in[1];
    const float* Wk = (const float*)d_in[2];
    const float* Wv = (const float*)d_in[3];
    const float* Wo = (const float*)d_in[4];
    float* out = (float*)d_out;

    char* ws = (char*)d_ws;
    // S region (47,185,920 B) at 0; hs_bf (16 MB) aliases its start (dead
    // before state_kernel writes S).
    unsigned short* STg   = (unsigned short*)ws;
    unsigned short* hs_bf = (unsigned short*)ws;
    size_t off = 47185920;
    unsigned short* qkv   = (unsigned short*)(ws + off); off += 25165824;  // 8192x1536
    unsigned short* Wqkv  = (unsigned short*)(ws + off); off += 3145728;   // 1536x1024
    unsigned short* Wo_bf = (unsigned short*)(ws + off); off += 2097152;   // total 77.6 MB

    cast_all<<<10752, 256, 0, stream>>>(hs, Wq, Wk, Wv, Wo, hs_bf, Wqkv, Wo_bf);
    // QKV projection: C[8192,1536] = hs_bf[8192,1024] @ Wqkv^T, 256^2 tiles
    gemm_bf16_8ph<unsigned short><<<dim3(6, 32), 512, 0, stream>>>(hs_bf, Wqkv, qkv,
                                                                   DM, DM, DM, QKVLD);
    state_kernel<<<1024, 256, 0, stream>>>(qkv, STg);
    scan_S<<<dim3(12, 64), 256, 0, stream>>>(STg);
    out_kernel<<<1024, 256, 0, stream>>>(qkv, STg, qkv);   // y in-place over v cols
    // output projection: out[8192,1024] = y[8192,1024] @ Wo^T
    gemm_bf16_8ph<float><<<dim3(4, 32), 512, 0, stream>>>(qkv + 512, Wo_bf, out,
                                                          DM, QKVLD, DM, DM);
}

// Round 2
// 201.901 us; speedup vs baseline: 1.0744x; 1.0548x over previous
//
#include <hip/hip_runtime.h>
#include <hip/hip_bf16.h>

#define BB 4
#define LL 2048
#define DM 1024
#define NH 16
#define FEAT 16
#define HD 64
#define CHUNK 128
#define NCHUNK 16
#define NEXT 80               // 64 v-cols + 1 ones-col + 15 pad
#define SROW 23040            // 18 dtiles x 80 e x 16 d = per-(bh,c) slab elems
#define EPS 1e-12f
#define INV_R2RD 0.17677669529663688f   // 1/(4*sqrt(2))
#define QKVLD 1536

typedef short bf16x8_t __attribute__((ext_vector_type(8)));
typedef float f32x4_t  __attribute__((ext_vector_type(4)));

__device__ __forceinline__ float b2f(unsigned short u) {
    union { unsigned int i; float f; } x; x.i = ((unsigned int)u) << 16; return x.f;
}
__device__ __forceinline__ unsigned short f2b(float f) {
    __hip_bfloat16 h = __float2bfloat16(f);
    return *reinterpret_cast<unsigned short*>(&h);
}

// ---------------------------------------------------------------------------
// One kernel for all fp32->bf16 casts (5 segments, compile-time boundaries).
// ---------------------------------------------------------------------------
__global__ __launch_bounds__(256)
void cast_all(const float* __restrict__ hs, const float* __restrict__ wq,
              const float* __restrict__ wk, const float* __restrict__ wv,
              const float* __restrict__ wo, unsigned short* __restrict__ hs_bf,
              unsigned short* __restrict__ wqkv, unsigned short* __restrict__ wo_bf)
{
    const int i = (blockIdx.x * 256 + threadIdx.x) * 4;
    const float* s; unsigned short* d;
    if (i < 8388608)       { s = hs + i;             d = hs_bf + i; }
    else if (i < 8650752)  { s = wq + (i - 8388608); d = wqkv + (i - 8388608); }
    else if (i < 8912896)  { s = wk + (i - 8650752); d = wqkv + 262144 + (i - 8650752); }
    else if (i < 9961472)  { s = wv + (i - 8912896); d = wqkv + 524288 + (i - 8912896); }
    else if (i < 11010048) { s = wo + (i - 9961472); d = wo_bf + (i - 9961472); }
    else return;
    float4 v = *(const float4*)s;
    ushort4 o; o.x = f2b(v.x); o.y = f2b(v.y); o.z = f2b(v.z); o.w = f2b(v.w);
    *(ushort4*)d = o;
}

// ---------------------------------------------------------------------------
// bf16 MFMA GEMM, 256x256 tile, BK=64, 8-phase counted-vmcnt schedule
// (m201 template: T2 XOR-swizzle + T3/T4 counted vmcnt + T5 setprio),
// + T1 bijective XCD-chunked blockIdx swizzle (nwg%8==0 required).
// C[M,N] = A[M,K] @ Bw[N,K]^T, fp32 acc. 512 threads = 8 waves (2M x 4N).
// ---------------------------------------------------------------------------
template <typename OutT>
__global__ __launch_bounds__(512, 2)
void gemm_bf16_8ph(const unsigned short* __restrict__ A, const unsigned short* __restrict__ Bw,
                   OutT* __restrict__ C, int K, int lda, int ldb, int ldc)
{
    __shared__ unsigned short lds[65536];   // 128 KiB
    const int tid  = threadIdx.x;
    const int wid  = tid >> 6, lane = tid & 63;
    const int wm   = wid >> 2, wn = wid & 3;
    const int ml   = lane & 15, quad = lane >> 4;
    // T1: XCD-chunked swizzle (dispatch id d -> XCD d%8; give each XCD a
    // contiguous tile range so neighbor blocks share A/B panels in its L2).
    const int nwg = gridDim.x * gridDim.y;
    const int lin = blockIdx.y * gridDim.x + blockIdx.x;
    const int swz_id = (lin & 7) * (nwg >> 3) + (lin >> 3);
    const int m0   = (swz_id / gridDim.x) * 256, n0 = (swz_id % gridDim.x) * 256;
    const int NT   = K >> 6;

    const int srow  = tid >> 3;                       // 0..63 row within 64-row load block
    const int scol  = ((tid & 7) ^ (srow & 7)) << 3;  // pre-swizzled col (elems)
    const int wbase = wid << 9;                       // wid*8 rows * 64 elems

    auto stage_half = [&](int t, int isB, int h) {
        const unsigned short* g0 = isB ? Bw : A;
        const int ld = isB ? ldb : lda;
        const int rb = (isB ? n0 : m0) + h * 128 + srow;
        const int k0 = t << 6;
        unsigned short* lb = lds + (isB ? 32768 : 0) + ((t & 1) << 14) + (h << 13) + wbase;
#pragma unroll
        for (int l = 0; l < 2; ++l) {
            const unsigned short* g = g0 + (size_t)(rb + l * 64) * ld + k0 + scol;
            __builtin_amdgcn_global_load_lds((const __attribute__((address_space(1))) void*)g,
                                             (__attribute__((address_space(3))) void*)(lb + l * 4096),
                                             16, 0, 0);
        }
    };

    f32x4_t acc[8][4];
#pragma unroll
    for (int i = 0; i < 8; ++i)
#pragma unroll
        for (int j = 0; j < 4; ++j) acc[i][j] = (f32x4_t){0.f, 0.f, 0.f, 0.f};

    // prologue: tile0 fully + tile1 {A0,B0,A1}; oldest 8 loads = tile0.
    stage_half(0, 0, 0); stage_half(0, 1, 0); stage_half(0, 0, 1); stage_half(0, 1, 1);
    stage_half(1, 0, 0); stage_half(1, 1, 0); stage_half(1, 0, 1);
    asm volatile("s_waitcnt vmcnt(6)" ::: "memory");
    __builtin_amdgcn_s_barrier();

    const int swz  = (ml & 7) << 3;
    const int c0   = (quad << 3) ^ swz;          // ks=0 frag col, swizzled
    const int c1   = (32 + (quad << 3)) ^ swz;   // ks=1
    const int arow = ml << 6;                     // ml * 64

    bf16x8_t aA[4][2], bLo[2][2], bHi[2][2];

    for (int t = 0; t < NT; ++t) {
        const int ab = (t & 1) << 14;
        const int bb = 32768 + ((t & 1) << 14);

        // ---- phase 0: read A-h0 (m0..3) + B-h0 (n0..1); stage (t+1,B,h1) ----
#pragma unroll
        for (int m = 0; m < 4; ++m) {
            const int r = ab + ((2 * m + wm) << 10) + arow;
            aA[m][0] = *(const bf16x8_t*)&lds[r + c0];
            aA[m][1] = *(const bf16x8_t*)&lds[r + c1];
        }
#pragma unroll
        for (int n = 0; n < 2; ++n) {
            const int r = bb + ((4 * n + wn) << 10) + arow;
            bLo[n][0] = *(const bf16x8_t*)&lds[r + c0];
            bLo[n][1] = *(const bf16x8_t*)&lds[r + c1];
        }
        if (t + 1 < NT) stage_half(t + 1, 1, 1);
        __builtin_amdgcn_s_barrier();
        asm volatile("s_waitcnt lgkmcnt(0)" ::: "memory");
        __builtin_amdgcn_sched_barrier(0);
        __builtin_amdgcn_s_setprio(1);
#pragma unroll
        for (int m = 0; m < 4; ++m)
#pragma unroll
            for (int n = 0; n < 2; ++n) {
                acc[m][n] = __builtin_amdgcn_mfma_f32_16x16x32_bf16(aA[m][0], bLo[n][0], acc[m][n], 0, 0, 0);
                acc[m][n] = __builtin_amdgcn_mfma_f32_16x16x32_bf16(aA[m][1], bLo[n][1], acc[m][n], 0, 0, 0);
            }
        __builtin_amdgcn_s_setprio(0);
        __builtin_amdgcn_s_barrier();

        // ---- phase 1: read B-h1 (n2..3); stage (t+2,A,h0) ----
#pragma unroll
        for (int n = 0; n < 2; ++n) {
            const int r = bb + ((4 * (n + 2) + wn) << 10) + arow;
            bHi[n][0] = *(const bf16x8_t*)&lds[r + c0];
            bHi[n][1] = *(const bf16x8_t*)&lds[r + c1];
        }
        if (t + 2 < NT) stage_half(t + 2, 0, 0);
        __builtin_amdgcn_s_barrier();
        asm volatile("s_waitcnt lgkmcnt(0)" ::: "memory");
        __builtin_amdgcn_sched_barrier(0);
        __builtin_amdgcn_s_setprio(1);
#pragma unroll
        for (int m = 0; m < 4; ++m)
#pragma unroll
            for (int n = 0; n < 2; ++n) {
                acc[m][2 + n] = __builtin_amdgcn_mfma_f32_16x16x32_bf16(aA[m][0], bHi[n][0], acc[m][2 + n], 0, 0, 0);
                acc[m][2 + n] = __builtin_amdgcn_mfma_f32_16x16x32_bf16(aA[m][1], bHi[n][1], acc[m][2 + n], 0, 0, 0);
            }
        __builtin_amdgcn_s_setprio(0);
        __builtin_amdgcn_s_barrier();

        // ---- phase 2: read A-h1 (m4..7, reuses aA regs); stage (t+2,B,h0) ----
#pragma unroll
        for (int m = 0; m < 4; ++m) {
            const int r = ab + ((2 * (m + 4) + wm) << 10) + arow;
            aA[m][0] = *(const bf16x8_t*)&lds[r + c0];
            aA[m][1] = *(const bf16x8_t*)&lds[r + c1];
        }
        if (t + 2 < NT) stage_half(t + 2, 1, 0);
        __builtin_amdgcn_s_barrier();
        asm volatile("s_waitcnt lgkmcnt(0)" ::: "memory");
        __builtin_amdgcn_sched_barrier(0);
        __builtin_amdgcn_s_setprio(1);
#pragma unroll
        for (int m = 0; m < 4; ++m)
#pragma unroll
            for (int n = 0; n < 2; ++n) {
                acc[4 + m][2 + n] = __builtin_amdgcn_mfma_f32_16x16x32_bf16(aA[m][0], bHi[n][0], acc[4 + m][2 + n], 0, 0, 0);
                acc[4 + m][2 + n] = __builtin_amdgcn_mfma_f32_16x16x32_bf16(aA[m][1], bHi[n][1], acc[4 + m][2 + n], 0, 0, 0);
            }
        __builtin_amdgcn_s_setprio(0);
        __builtin_amdgcn_s_barrier();

        // ---- phase 3: no reads; stage (t+2,A,h1); boundary vmcnt ----
        if (t + 2 < NT) stage_half(t + 2, 0, 1);
        __builtin_amdgcn_s_barrier();
        asm volatile("s_waitcnt lgkmcnt(0)" ::: "memory");
        __builtin_amdgcn_sched_barrier(0);
        __builtin_amdgcn_s_setprio(1);
#pragma unroll
        for (int m = 0; m < 4; ++m)
#pragma unroll
            for (int n = 0; n < 2; ++n) {
                acc[4 + m][n] = __builtin_amdgcn_mfma_f32_16x16x32_bf16(aA[m][0], bLo[n][0], acc[4 + m][n], 0, 0, 0);
                acc[4 + m][n] = __builtin_amdgcn_mfma_f32_16x16x32_bf16(aA[m][1], bLo[n][1], acc[4 + m][n], 0, 0, 0);
            }
        __builtin_amdgcn_s_setprio(0);
        if (t + 2 < NT)      asm volatile("s_waitcnt vmcnt(6)" ::: "memory");
        else if (t + 1 < NT) asm volatile("s_waitcnt vmcnt(0)" ::: "memory");
        __builtin_amdgcn_s_barrier();
    }

    // ---- epilogue: C write ----
#pragma unroll
    for (int m = 0; m < 8; ++m) {
        const int rbase = m0 + (2 * m + wm) * 16 + quad * 4;
#pragma unroll
        for (int n = 0; n < 4; ++n) {
            const int col = n0 + (4 * n + wn) * 16 + ml;
#pragma unroll
            for (int r = 0; r < 4; ++r) {
                const float v = acc[m][n][r];
                if constexpr (sizeof(OutT) == 2) {
                    ((unsigned short*)C)[(size_t)(rbase + r) * ldc + col] = f2b(v);
                } else {
                    ((float*)C)[(size_t)(rbase + r) * ldc + col] = v;
                }
            }
        }
    }
}

// ---------------------------------------------------------------------------
// 128x256-tile variant (fp32 out) for the output projection: N=1024 gives
// only 128 blocks at 256^2 (half the CUs idle); 128x256 -> grid 4x64 = 256
// blocks = full chip. 512 threads = 8 waves (2M x 4N), per-wave 64x64 out.
// LDS 96 KiB: A[2][128][64] @0, B[2][256][64] @16384 (ushort). Same XOR
// swizzle / pre-swizzled-global staging. 2 phases/K-tile, 16 MFMA each.
// Staging units (512thr x 16B = 4096 elems = 64 rows): A=2, B=4 per tile.
//   p0: stage (t+1, B, units 2,3)   [B-hi, read in p1 of t-1]
//   p1: stage (t+2, A, 0,1) + (t+2, B, 0,1) [read in p0 of t]
// boundary vmcnt(4): drains t+1's 6 units, leaves t+2's 4 in flight.
// ---------------------------------------------------------------------------
__global__ __launch_bounds__(512, 2)
void gemm_bf16_128x256(const unsigned short* __restrict__ A, const unsigned short* __restrict__ Bw,
                       float* __restrict__ C, int K, int lda, int ldb, int ldc)
{
    __shared__ unsigned short lds[49152];   // 96 KiB
    const int tid  = threadIdx.x;
    const int wid  = tid >> 6, lane = tid & 63;
    const int wm   = wid >> 2, wn = wid & 3;
    const int ml   = lane & 15, quad = lane >> 4;
    const int nwg = gridDim.x * gridDim.y;
    const int lin = blockIdx.y * gridDim.x + blockIdx.x;
    const int swz_id = (lin & 7) * (nwg >> 3) + (lin >> 3);
    const int m0   = (swz_id / gridDim.x) * 128, n0 = (swz_id % gridDim.x) * 256;
    const int NT   = K >> 6;

    const int srow  = tid >> 3;
    const int scol  = ((tid & 7) ^ (srow & 7)) << 3;
    const int wbase = wid << 9;

    // unit u covers rows u*64..u*64+63 of the A (u<2) or B (u<4) tile.
    auto stage_unit = [&](int t, int isB, int u) {
        const unsigned short* g0 = isB ? Bw : A;
        const int ld = isB ? ldb : lda;
        const int rb = (isB ? n0 : m0) + u * 64 + srow;
        const int k0 = t << 6;
        unsigned short* lb = lds + (isB ? 16384 : 0) + ((t & 1) << (isB ? 14 : 13))
                             + (u << 12) + wbase;
        const unsigned short* g = g0 + (size_t)rb * ld + k0 + scol;
        __builtin_amdgcn_global_load_lds((const __attribute__((address_space(1))) void*)g,
                                         (__attribute__((address_space(3))) void*)lb, 16, 0, 0);
    };

    f32x4_t acc[4][4];
#pragma unroll
    for (int i = 0; i < 4; ++i)
#pragma unroll
        for (int j = 0; j < 4; ++j) acc[i][j] = (f32x4_t){0.f, 0.f, 0.f, 0.f};

    // prologue: tile0 all 6 units, tile1 {A0,A1,B0,B1}; vmcnt(4) drains t0.
    stage_unit(0, 0, 0); stage_unit(0, 0, 1);
    stage_unit(0, 1, 0); stage_unit(0, 1, 1); stage_unit(0, 1, 2); stage_unit(0, 1, 3);
    stage_unit(1, 0, 0); stage_unit(1, 0, 1);
    stage_unit(1, 1, 0); stage_unit(1, 1, 1);
    asm volatile("s_waitcnt vmcnt(4)" ::: "memory");
    __builtin_amdgcn_s_barrier();

    const int swz  = (ml & 7) << 3;
    const int c0   = (quad << 3) ^ swz;
    const int c1   = (32 + (quad << 3)) ^ swz;
    const int arow = ml << 6;

    bf16x8_t aA[4][2], bF[2][2];

    for (int t = 0; t < NT; ++t) {
        const int ab = (t & 1) << 13;
        const int bb = 16384 + ((t & 1) << 14);

        // ---- phase 0: read A (m0..3) + B-lo (n0..1); stage (t+1,B,u2,u3) ----
#pragma unroll
        for (int m = 0; m < 4; ++m) {
            const int r = ab + ((2 * m + wm) << 10) + arow;
            aA[m][0] = *(const bf16x8_t*)&lds[r + c0];
            aA[m][1] = *(const bf16x8_t*)&lds[r + c1];
        }
#pragma unroll
        for (int n = 0; n < 2; ++n) {
            const int r = bb + ((4 * n + wn) << 10) + arow;
            bF[n][0] = *(const bf16x8_t*)&lds[r + c0];
            bF[n][1] = *(const bf16x8_t*)&lds[r + c1];
        }
        if (t + 1 < NT) { stage_unit(t + 1, 1, 2); stage_unit(t + 1, 1, 3); }
        __builtin_amdgcn_s_barrier();
        asm volatile("s_waitcnt lgkmcnt(0)" ::: "memory");
        __builtin_amdgcn_sched_barrier(0);
        __builtin_amdgcn_s_setprio(1);
#pragma unroll
        for (int m = 0; m < 4; ++m)
#pragma unroll
            for (int n = 0; n < 2; ++n) {
                acc[m][n] = __builtin_amdgcn_mfma_f32_16x16x32_bf16(aA[m][0], bF[n][0], acc[m][n], 0, 0, 0);
                acc[m][n] = __builtin_amdgcn_mfma_f32_16x16x32_bf16(aA[m][1], bF[n][1], acc[m][n], 0, 0, 0);
            }
        __builtin_amdgcn_s_setprio(0);
        __builtin_amdgcn_s_barrier();

        // ---- phase 1: read B-hi (n2..3); stage (t+2,A,0,1)+(t+2,B,0,1) ----
#pragma unroll
        for (int n = 0; n < 2; ++n) {
            const int r = bb + ((4 * (n + 2) + wn) << 10) + arow;
            bF[n][0] = *(const bf16x8_t*)&lds[r + c0];
            bF[n][1] = *(const bf16x8_t*)&lds[r + c1];
        }
        if (t + 2 < NT) {
            stage_unit(t + 2, 0, 0); stage_unit(t + 2, 0, 1);
            stage_unit(t + 2, 1, 0); stage_unit(t + 2, 1, 1);
        }
        __builtin_amdgcn_s_barrier();
        asm volatile("s_waitcnt lgkmcnt(0)" ::: "memory");
        __builtin_amdgcn_sched_barrier(0);
        __builtin_amdgcn_s_setprio(1);
#pragma unroll
        for (int m = 0; m < 4; ++m)
#pragma unroll
            for (int n = 0; n < 2; ++n) {
                acc[m][2 + n] = __builtin_amdgcn_mfma_f32_16x16x32_bf16(aA[m][0], bF[n][0], acc[m][2 + n], 0, 0, 0);
                acc[m][2 + n] = __builtin_amdgcn_mfma_f32_16x16x32_bf16(aA[m][1], bF[n][1], acc[m][2 + n], 0, 0, 0);
            }
        __builtin_amdgcn_s_setprio(0);
        if (t + 2 < NT)      asm volatile("s_waitcnt vmcnt(4)" ::: "memory");
        else if (t + 1 < NT) asm volatile("s_waitcnt vmcnt(0)" ::: "memory");
        __builtin_amdgcn_s_barrier();
    }

    // ---- epilogue: fp32 C write ----
#pragma unroll
    for (int m = 0; m < 4; ++m) {
        const int rbase = m0 + (2 * m + wm) * 16 + quad * 4;
#pragma unroll
        for (int n = 0; n < 4; ++n) {
            const int col = n0 + (4 * n + wn) * 16 + ml;
#pragma unroll
            for (int r = 0; r < 4; ++r)
                C[(size_t)(rbase + r) * ldc + col] = acc[m][n][r];
        }
    }
}

// ---------------------------------------------------------------------------
// state_kernel: per (bh,c) computes S_c = Kf^T @ V_ext (MFMA), stored in the
// TILED layout: slab[dtile 0..17][e 0..79][dlocal 0..15], d = dtile*16+dlocal.
// Feature order d: [1][q/2 x16][0 x7][qxq/(4sqrt2) x256][0 x8]; e=64 -> z.
// ---------------------------------------------------------------------------
__global__ __launch_bounds__(256)
void state_kernel(const unsigned short* __restrict__ qkv, unsigned short* __restrict__ STg)
{
    __shared__ unsigned short KT[16 * 136];   // K transposed [f][j], padded
    __shared__ unsigned short VT[80 * 136];   // V_ext transposed [e][j], padded

    const int x = blockIdx.x;
    const int c = x & 15, bh = x >> 4;
    const int b = bh >> 4, h = bh & 15;
    const int tid = threadIdx.x;
    const int wave = tid >> 6, lane = tid & 63;
    const int ml = lane & 15, kg8 = (lane >> 4) * 8;
    const size_t rowbase = (size_t)(b * LL + c * CHUNK);
    const size_t Sbase = (size_t)x * SROW;

    {
        const int row = tid >> 1, half = tid & 1;
        uint4 kv = *(const uint4*)(qkv + (rowbase + row) * QKVLD + 256 + h * 16 + half * 8);
        const unsigned short* kp = (const unsigned short*)&kv;
#pragma unroll
        for (int i = 0; i < 8; ++i) KT[(half * 8 + i) * 136 + row] = kp[i];
#pragma unroll
        for (int cc = 0; cc < 4; ++cc) {
            uint4 vv = *(const uint4*)(qkv + (rowbase + row) * QKVLD + 512 + h * 64 + half * 32 + cc * 8);
            const unsigned short* vp = (const unsigned short*)&vv;
#pragma unroll
            for (int i = 0; i < 8; ++i) VT[(half * 32 + cc * 8 + i) * 136 + row] = vp[i];
        }
        if (half == 0) {
            VT[64 * 136 + row] = 0x3F80;   // ones column
        } else {
#pragma unroll
            for (int e = 65; e < 80; ++e) VT[e * 136 + row] = 0;
        }
    }
    __syncthreads();

    bf16x8_t bfr[5][4];
#pragma unroll
    for (int nt = 0; nt < 5; ++nt)
#pragma unroll
        for (int ks = 0; ks < 4; ++ks)
            bfr[nt][ks] = *(const bf16x8_t*)&VT[(nt * 16 + ml) * 136 + ks * 32 + kg8];

    for (int mt = wave; mt < 18; mt += 4) {
        const int d = mt * 16 + ml;
        bf16x8_t af[4];
#pragma unroll
        for (int ks = 0; ks < 4; ++ks) {
            const int jb = ks * 32 + kg8;
            unsigned short o[8];
            if (d >= 24 && d < 280) {
                const int e = d - 24, a = e >> 4, bq = e & 15;
                bf16x8_t ka = *(const bf16x8_t*)&KT[a  * 136 + jb];
                bf16x8_t kb = *(const bf16x8_t*)&KT[bq * 136 + jb];
#pragma unroll
                for (int j = 0; j < 8; ++j)
                    o[j] = f2b(b2f((unsigned short)ka[j]) * b2f((unsigned short)kb[j]) * INV_R2RD);
            } else if (d == 0) {
#pragma unroll
                for (int j = 0; j < 8; ++j) o[j] = 0x3F80;
            } else if (d <= 16) {
                bf16x8_t kx = *(const bf16x8_t*)&KT[(d - 1) * 136 + jb];
#pragma unroll
                for (int j = 0; j < 8; ++j) o[j] = f2b(b2f((unsigned short)kx[j]) * 0.5f);
            } else {
#pragma unroll
                for (int j = 0; j < 8; ++j) o[j] = 0;
            }
            af[ks] = *(const bf16x8_t*)o;
        }
        f32x4_t acc[5];
#pragma unroll
        for (int nt = 0; nt < 5; ++nt) acc[nt] = (f32x4_t){0.f, 0.f, 0.f, 0.f};
        __builtin_amdgcn_s_setprio(1);
#pragma unroll
        for (int nt = 0; nt < 5; ++nt)
#pragma unroll
            for (int ks = 0; ks < 4; ++ks)
                acc[nt] = __builtin_amdgcn_mfma_f32_16x16x32_bf16(af[ks], bfr[nt][ks], acc[nt], 0, 0, 0);
        __builtin_amdgcn_s_setprio(0);
        // tiled store: slab[mt][e = nt*16+ml][dlocal = quad*4 + r]
#pragma unroll
        for (int nt = 0; nt < 5; ++nt) {
            ushort4 pk;
            pk.x = f2b(acc[nt][0]); pk.y = f2b(acc[nt][1]);
            pk.z = f2b(acc[nt][2]); pk.w = f2b(acc[nt][3]);
            *(ushort4*)(STg + Sbase + (size_t)mt * 1280 + (nt * 16 + ml) * 16 + (lane >> 4) * 4) = pk;
        }
    }
}

// ---------------------------------------------------------------------------
// scan: exclusive prefix over the 16 chunks, elementwise, uint4 per thread.
// All 16 chunk loads issued up-front (parallel, one HBM round-trip) instead
// of a 16-deep read->acc->write latency chain; then convert+accumulate+store.
// ---------------------------------------------------------------------------
__global__ __launch_bounds__(256)
void scan_S(unsigned short* __restrict__ STg) {
    const int bh  = blockIdx.y;
    const int idx = blockIdx.x * 256 + threadIdx.x;   // uint4 index, 0..2879
    if (idx >= SROW / 8) return;
    const size_t base = (size_t)bh * NCHUNK * SROW + (size_t)idx * 8;
    uint4 v[NCHUNK];
#pragma unroll
    for (int c = 0; c < NCHUNK; ++c)
        v[c] = *(const uint4*)(STg + base + (size_t)c * SROW);
    float acc[8] = {};
#pragma unroll
    for (int c = 0; c < NCHUNK; ++c) {
        const unsigned short* vp = (const unsigned short*)&v[c];
        uint4 o;
        unsigned short* op = (unsigned short*)&o;
#pragma unroll
        for (int i = 0; i < 8; ++i) { op[i] = f2b(acc[i]); acc[i] += b2f(vp[i]); }
        *(uint4*)(STg + base + (size_t)c * SROW) = o;
    }
}

// ---------------------------------------------------------------------------
// out_kernel: per (bh,c), 256 threads / 4 waves.
// Phase 1: A = poly(Q K^T / 4) masked (MFMA), A staged bf16 in LDS.
// Phase 2a: Y += A @ V_ext (MFMA, VT in LDS).
// Phase 2b: Y += Qf @ S_ext — BARRIER-FREE: B-fragments loaded directly
//   global->VGPR from the tiled ST slab, double-buffered (prefetch kq+1
//   during MFMA of kq; slice 0 issued at kernel top).
// LDS (ushort units): Qpad[128*40]@0 + Kpad[128*40]@5120 (VT[80*136]@0
// overlays both after phase 1) | A[128*136]@10880 | Qs[128*16]@28288.
// ---------------------------------------------------------------------------
#define OFF_VT 0
#define OFF_QP 0
#define OFF_KP 5120
#define OFF_A  10880
#define OFF_QS 28288

__global__ __launch_bounds__(256)
void out_kernel(const unsigned short* __restrict__ qkv_ro, const unsigned short* __restrict__ STg,
                unsigned short* __restrict__ qkv_w)
{
    __shared__ unsigned short smem[30336];   // 60672 B

    const int x = blockIdx.x;
    const int c = x & 15, bh = x >> 4;
    const int b = bh >> 4, h = bh & 15;
    const int tid = threadIdx.x;
    const int w = tid >> 6, lane = tid & 63;
    const int ml = lane & 15, quad = lane >> 4, kg8 = quad * 8;
    const size_t rowbase = (size_t)(b * LL + c * CHUNK);
    const size_t Sbase = (size_t)x * SROW;

    // ---- early prefetch of ST slice kq=0 (in flight through phase 1) ----
    const unsigned short* stp = STg + Sbase + (size_t)(quad >> 1) * 1280 + (quad & 1) * 8;
    bf16x8_t stf[2][5];
#pragma unroll
    for (int nt = 0; nt < 5; ++nt)
        stf[0][nt] = *(const bf16x8_t*)(stp + (nt * 16 + ml) * 16);

    // ---- load Q (padded + small) and K (padded) ----
    {
        const int row = tid >> 1, half = tid & 1;
        uint4 qv = *(const uint4*)(qkv_ro + (rowbase + row) * QKVLD + h * 16 + half * 8);
        *(uint4*)&smem[OFF_QP + row * 40 + half * 8] = qv;
        *(uint4*)&smem[OFF_QP + row * 40 + 16 + half * 8] = (uint4){0, 0, 0, 0};
        *(uint4*)&smem[OFF_QS + row * 16 + half * 8] = qv;
        uint4 kv = *(const uint4*)(qkv_ro + (rowbase + row) * QKVLD + 256 + h * 16 + half * 8);
        *(uint4*)&smem[OFF_KP + row * 40 + half * 8] = kv;
        *(uint4*)&smem[OFF_KP + row * 40 + 16 + half * 8] = (uint4){0, 0, 0, 0};
    }
    __syncthreads();

    // ---- phase 1: scores ----
    {
        bf16x8_t q0 = *(const bf16x8_t*)&smem[OFF_QP + (w * 32 + ml) * 40 + kg8];
        bf16x8_t q1 = *(const bf16x8_t*)&smem[OFF_QP + (w * 32 + 16 + ml) * 40 + kg8];
#pragma unroll
        for (int nt = 0; nt < 8; ++nt) {
            bf16x8_t kf = *(const bf16x8_t*)&smem[OFF_KP + (nt * 16 + ml) * 40 + kg8];
            f32x4_t a0 = __builtin_amdgcn_mfma_f32_16x16x32_bf16(q0, kf, (f32x4_t){0,0,0,0}, 0, 0, 0);
            f32x4_t a1 = __builtin_amdgcn_mfma_f32_16x16x32_bf16(q1, kf, (f32x4_t){0,0,0,0}, 0, 0, 0);
            const int j = nt * 16 + ml;
#pragma unroll
            for (int r = 0; r < 4; ++r) {
                int i0 = w * 32 + quad * 4 + r;
                float s0 = a0[r] * 0.25f;
                float v0 = (j <= i0) ? (1.f + s0 + 0.5f * s0 * s0) : 0.f;
                smem[OFF_A + i0 * 136 + j] = f2b(v0);
                int i1 = i0 + 16;
                float s1 = a1[r] * 0.25f;
                float v1 = (j <= i1) ? (1.f + s1 + 0.5f * s1 * s1) : 0.f;
                smem[OFF_A + i1 * 136 + j] = f2b(v1);
            }
        }
    }
    // q f32 registers for Qf build
    const int r0 = w * 32 + ml, r1 = r0 + 16;
    float qA[16], qB[16];
    {
        bf16x8_t t0 = *(const bf16x8_t*)&smem[OFF_QS + r0 * 16];
        bf16x8_t t1 = *(const bf16x8_t*)&smem[OFF_QS + r0 * 16 + 8];
        bf16x8_t t2 = *(const bf16x8_t*)&smem[OFF_QS + r1 * 16];
        bf16x8_t t3 = *(const bf16x8_t*)&smem[OFF_QS + r1 * 16 + 8];
#pragma unroll
        for (int i = 0; i < 8; ++i) {
            qA[i] = b2f((unsigned short)t0[i]); qA[8 + i] = b2f((unsigned short)t1[i]);
            qB[i] = b2f((unsigned short)t2[i]); qB[8 + i] = b2f((unsigned short)t3[i]);
        }
    }
    __syncthreads();   // A-writes + Qpad/Kpad reads done before VT overlay

    // ---- load VT (overlays Qpad/Kpad) ----
    {
        const int row = tid >> 1, half = tid & 1;
#pragma unroll
        for (int cc = 0; cc < 4; ++cc) {
            uint4 vv = *(const uint4*)(qkv_ro + (rowbase + row) * QKVLD + 512 + h * 64 + half * 32 + cc * 8);
            const unsigned short* vp = (const unsigned short*)&vv;
#pragma unroll
            for (int i = 0; i < 8; ++i) smem[OFF_VT + (half * 32 + cc * 8 + i) * 136 + row] = vp[i];
        }
        if (half == 0) {
            smem[OFF_VT + 64 * 136 + row] = 0x3F80;
        } else {
#pragma unroll
            for (int e = 65; e < 80; ++e) smem[OFF_VT + e * 136 + row] = 0;
        }
    }
    __syncthreads();

    f32x4_t acc[2][5];
#pragma unroll
    for (int mt = 0; mt < 2; ++mt)
#pragma unroll
        for (int nt = 0; nt < 5; ++nt) acc[mt][nt] = (f32x4_t){0.f, 0.f, 0.f, 0.f};

    // ---- phase 2a: A @ V_ext ----
#pragma unroll
    for (int ks = 0; ks < 4; ++ks) {
        bf16x8_t af0 = *(const bf16x8_t*)&smem[OFF_A + (w * 32 + ml) * 136 + ks * 32 + kg8];
        bf16x8_t af1 = *(const bf16x8_t*)&smem[OFF_A + (w * 32 + 16 + ml) * 136 + ks * 32 + kg8];
        __builtin_amdgcn_s_setprio(1);
#pragma unroll
        for (int nt = 0; nt < 5; ++nt) {
            bf16x8_t bv = *(const bf16x8_t*)&smem[OFF_VT + (nt * 16 + ml) * 136 + ks * 32 + kg8];
            acc[0][nt] = __builtin_amdgcn_mfma_f32_16x16x32_bf16(af0, bv, acc[0][nt], 0, 0, 0);
            acc[1][nt] = __builtin_amdgcn_mfma_f32_16x16x32_bf16(af1, bv, acc[1][nt], 0, 0, 0);
        }
        __builtin_amdgcn_s_setprio(0);
    }

    // ---- phase 2b: Qf @ S_ext, barrier-free, double-buffered global reads ----
#pragma unroll
    for (int kq = 0; kq < 9; ++kq) {
        if (kq < 8) {
#pragma unroll
            for (int nt = 0; nt < 5; ++nt)
                stf[(kq + 1) & 1][nt] =
                    *(const bf16x8_t*)(stp + (size_t)(kq + 1) * 2560 + (nt * 16 + ml) * 16);
        }
        bf16x8_t qf[2];
#pragma unroll
        for (int mt = 0; mt < 2; ++mt) {
            const float* q = (mt == 0) ? qA : qB;
            const int qsrow = (mt == 0) ? r0 : r1;
            const int d0 = kq * 32 + kg8;
            unsigned short o[8];
            if (d0 >= 24 && d0 < 280) {
                const int e0 = d0 - 24;
                const float qa = b2f(smem[OFF_QS + qsrow * 16 + (e0 >> 4)]) * INV_R2RD;
                if ((e0 & 15) == 0) {
#pragma unroll
                    for (int j = 0; j < 8; ++j) o[j] = f2b(qa * q[j]);
                } else {
#pragma unroll
                    for (int j = 0; j < 8; ++j) o[j] = f2b(qa * q[8 + j]);
                }
            } else if (d0 == 0) {
                o[0] = 0x3F80;
#pragma unroll
                for (int j = 1; j < 8; ++j) o[j] = f2b(q[j - 1] * 0.5f);
            } else if (d0 == 8) {
#pragma unroll
                for (int j = 0; j < 8; ++j) o[j] = f2b(q[7 + j] * 0.5f);
            } else if (d0 == 16) {
                o[0] = f2b(q[15] * 0.5f);
#pragma unroll
                for (int j = 1; j < 8; ++j) o[j] = 0;
            } else {
#pragma unroll
                for (int j = 0; j < 8; ++j) o[j] = 0;
            }
            qf[mt] = *(const bf16x8_t*)o;
        }
        __builtin_amdgcn_s_setprio(1);
#pragma unroll
        for (int nt = 0; nt < 5; ++nt) {
            acc[0][nt] = __builtin_amdgcn_mfma_f32_16x16x32_bf16(qf[0], stf[kq & 1][nt], acc[0][nt], 0, 0, 0);
            acc[1][nt] = __builtin_amdgcn_mfma_f32_16x16x32_bf16(qf[1], stf[kq & 1][nt], acc[1][nt], 0, 0, 0);
        }
        __builtin_amdgcn_s_setprio(0);
    }

    // ---- epilogue: y = num / (den + eps), den = col 64 (nt=4, ml==0 lanes) ----
#pragma unroll
    for (int mt = 0; mt < 2; ++mt) {
        float den[4];
#pragma unroll
        for (int r = 0; r < 4; ++r) den[r] = __shfl(acc[mt][4][r], lane & 48);
#pragma unroll
        for (int r = 0; r < 4; ++r) {
            const size_t grow = rowbase + w * 32 + mt * 16 + quad * 4 + r;
            const float rc = 1.f / (den[r] + EPS);
#pragma unroll
            for (int nt = 0; nt < 4; ++nt)
                qkv_w[grow * QKVLD + 512 + h * 64 + nt * 16 + ml] = f2b(acc[mt][nt][r] * rc);
        }
    }
}

// ---------------------------------------------------------------------------
extern "C" void kernel_launch(void* const* d_in, const int* in_sizes, int n_in,
                              void* d_out, int out_size, void* d_ws, size_t ws_size,
                              hipStream_t stream)
{
    (void)in_sizes; (void)n_in; (void)out_size; (void)ws_size;
    const float* hs = (const float*)d_in[0];
    const float* Wq = (const float*)d_in[1];
    const float* Wk = (const float*)d_in[2];
    const float* Wv = (const float*)d_in[3];
    const float* Wo = (const float*)d_in[4];
    float* out = (float*)d_out;

    char* ws = (char*)d_ws;
    // S region (47,185,920 B) at 0; hs_bf (16 MB) aliases its start (dead
    // before state_kernel writes S).
    unsigned short* STg   = (unsigned short*)ws;
    unsigned short* hs_bf = (unsigned short*)ws;
    size_t off = 47185920;
    unsigned short* qkv   = (unsigned short*)(ws + off); off += 25165824;  // 8192x1536
    unsigned short* Wqkv  = (unsigned short*)(ws + off); off += 3145728;   // 1536x1024
    unsigned short* Wo_bf = (unsigned short*)(ws + off); off += 2097152;   // total 77.6 MB

    cast_all<<<10752, 256, 0, stream>>>(hs, Wq, Wk, Wv, Wo, hs_bf, Wqkv, Wo_bf);
    // QKV projection: C[8192,1536] = hs_bf[8192,1024] @ Wqkv^T, 256^2 tiles
    gemm_bf16_8ph<unsigned short><<<dim3(6, 32), 512, 0, stream>>>(hs_bf, Wqkv, qkv,
                                                                   DM, DM, DM, QKVLD);
    state_kernel<<<1024, 256, 0, stream>>>(qkv, STg);
    scan_S<<<dim3(12, 64), 256, 0, stream>>>(STg);
    out_kernel<<<1024, 256, 0, stream>>>(qkv, STg, qkv);   // y in-place over v cols
    // output projection: out[8192,1024] = y[8192,1024] @ Wo^T, 128x256 tiles,
    // grid 4x64 = 256 blocks (full chip; 256^2 gave only 128 blocks).
    gemm_bf16_128x256<<<dim3(4, 64), 512, 0, stream>>>(qkv + 512, Wo_bf, out,
                                                       DM, QKVLD, DM, DM);
}

// Round 3
// 198.306 us; speedup vs baseline: 1.0939x; 1.0181x over previous
//
#include <hip/hip_runtime.h>
#include <hip/hip_bf16.h>

#define BB 4
#define LL 2048
#define DM 1024
#define NH 16
#define FEAT 16
#define HD 64
#define CHUNK 128
#define NCHUNK 16
#define NEXT 65               // 64 v-cols + 1 ones-col (e=65..79 zeros dropped)
#define SROW 18720            // 18 dtiles x 65 e x 16 d = per-(bh,c) slab elems
#define EPS 1e-12f
#define INV_R2RD 0.17677669529663688f   // 1/(4*sqrt(2))
#define QKVLD 1536

typedef short bf16x8_t __attribute__((ext_vector_type(8)));
typedef float f32x4_t  __attribute__((ext_vector_type(4)));

__device__ __forceinline__ float b2f(unsigned short u) {
    union { unsigned int i; float f; } x; x.i = ((unsigned int)u) << 16; return x.f;
}
__device__ __forceinline__ unsigned short f2b(float f) {
    __hip_bfloat16 h = __float2bfloat16(f);
    return *reinterpret_cast<unsigned short*>(&h);
}

// ---------------------------------------------------------------------------
// One kernel for all fp32->bf16 casts (5 segments, compile-time boundaries).
// ---------------------------------------------------------------------------
__global__ __launch_bounds__(256)
void cast_all(const float* __restrict__ hs, const float* __restrict__ wq,
              const float* __restrict__ wk, const float* __restrict__ wv,
              const float* __restrict__ wo, unsigned short* __restrict__ hs_bf,
              unsigned short* __restrict__ wqkv, unsigned short* __restrict__ wo_bf)
{
    const int i = (blockIdx.x * 256 + threadIdx.x) * 4;
    const float* s; unsigned short* d;
    if (i < 8388608)       { s = hs + i;             d = hs_bf + i; }
    else if (i < 8650752)  { s = wq + (i - 8388608); d = wqkv + (i - 8388608); }
    else if (i < 8912896)  { s = wk + (i - 8650752); d = wqkv + 262144 + (i - 8650752); }
    else if (i < 9961472)  { s = wv + (i - 8912896); d = wqkv + 524288 + (i - 8912896); }
    else if (i < 11010048) { s = wo + (i - 9961472); d = wo_bf + (i - 9961472); }
    else return;
    float4 v = *(const float4*)s;
    ushort4 o; o.x = f2b(v.x); o.y = f2b(v.y); o.z = f2b(v.z); o.w = f2b(v.w);
    *(ushort4*)d = o;
}

// ---------------------------------------------------------------------------
// bf16 MFMA GEMM, 256x256 tile, BK=64, 8-phase counted-vmcnt schedule
// (m201 template: T2 XOR-swizzle + T3/T4 counted vmcnt + T5 setprio),
// + T1 bijective XCD-chunked blockIdx swizzle (nwg%8==0 required).
// C[M,N] = A[M,K] @ Bw[N,K]^T, fp32 acc. 512 threads = 8 waves (2M x 4N).
// ---------------------------------------------------------------------------
template <typename OutT>
__global__ __launch_bounds__(512, 2)
void gemm_bf16_8ph(const unsigned short* __restrict__ A, const unsigned short* __restrict__ Bw,
                   OutT* __restrict__ C, int K, int lda, int ldb, int ldc)
{
    __shared__ unsigned short lds[65536];   // 128 KiB
    const int tid  = threadIdx.x;
    const int wid  = tid >> 6, lane = tid & 63;
    const int wm   = wid >> 2, wn = wid & 3;
    const int ml   = lane & 15, quad = lane >> 4;
    const int nwg = gridDim.x * gridDim.y;
    const int lin = blockIdx.y * gridDim.x + blockIdx.x;
    const int swz_id = (lin & 7) * (nwg >> 3) + (lin >> 3);
    const int m0   = (swz_id / gridDim.x) * 256, n0 = (swz_id % gridDim.x) * 256;
    const int NT   = K >> 6;

    const int srow  = tid >> 3;                       // 0..63 row within 64-row load block
    const int scol  = ((tid & 7) ^ (srow & 7)) << 3;  // pre-swizzled col (elems)
    const int wbase = wid << 9;                       // wid*8 rows * 64 elems

    auto stage_half = [&](int t, int isB, int h) {
        const unsigned short* g0 = isB ? Bw : A;
        const int ld = isB ? ldb : lda;
        const int rb = (isB ? n0 : m0) + h * 128 + srow;
        const int k0 = t << 6;
        unsigned short* lb = lds + (isB ? 32768 : 0) + ((t & 1) << 14) + (h << 13) + wbase;
#pragma unroll
        for (int l = 0; l < 2; ++l) {
            const unsigned short* g = g0 + (size_t)(rb + l * 64) * ld + k0 + scol;
            __builtin_amdgcn_global_load_lds((const __attribute__((address_space(1))) void*)g,
                                             (__attribute__((address_space(3))) void*)(lb + l * 4096),
                                             16, 0, 0);
        }
    };

    f32x4_t acc[8][4];
#pragma unroll
    for (int i = 0; i < 8; ++i)
#pragma unroll
        for (int j = 0; j < 4; ++j) acc[i][j] = (f32x4_t){0.f, 0.f, 0.f, 0.f};

    // prologue: tile0 fully + tile1 {A0,B0,A1}; oldest 8 loads = tile0.
    stage_half(0, 0, 0); stage_half(0, 1, 0); stage_half(0, 0, 1); stage_half(0, 1, 1);
    stage_half(1, 0, 0); stage_half(1, 1, 0); stage_half(1, 0, 1);
    asm volatile("s_waitcnt vmcnt(6)" ::: "memory");
    __builtin_amdgcn_s_barrier();

    const int swz  = (ml & 7) << 3;
    const int c0   = (quad << 3) ^ swz;          // ks=0 frag col, swizzled
    const int c1   = (32 + (quad << 3)) ^ swz;   // ks=1
    const int arow = ml << 6;                     // ml * 64

    bf16x8_t aA[4][2], bLo[2][2], bHi[2][2];

    for (int t = 0; t < NT; ++t) {
        const int ab = (t & 1) << 14;
        const int bb = 32768 + ((t & 1) << 14);

        // ---- phase 0: read A-h0 (m0..3) + B-h0 (n0..1); stage (t+1,B,h1) ----
#pragma unroll
        for (int m = 0; m < 4; ++m) {
            const int r = ab + ((2 * m + wm) << 10) + arow;
            aA[m][0] = *(const bf16x8_t*)&lds[r + c0];
            aA[m][1] = *(const bf16x8_t*)&lds[r + c1];
        }
#pragma unroll
        for (int n = 0; n < 2; ++n) {
            const int r = bb + ((4 * n + wn) << 10) + arow;
            bLo[n][0] = *(const bf16x8_t*)&lds[r + c0];
            bLo[n][1] = *(const bf16x8_t*)&lds[r + c1];
        }
        if (t + 1 < NT) stage_half(t + 1, 1, 1);
        __builtin_amdgcn_s_barrier();
        asm volatile("s_waitcnt lgkmcnt(0)" ::: "memory");
        __builtin_amdgcn_sched_barrier(0);
        __builtin_amdgcn_s_setprio(1);
#pragma unroll
        for (int m = 0; m < 4; ++m)
#pragma unroll
            for (int n = 0; n < 2; ++n) {
                acc[m][n] = __builtin_amdgcn_mfma_f32_16x16x32_bf16(aA[m][0], bLo[n][0], acc[m][n], 0, 0, 0);
                acc[m][n] = __builtin_amdgcn_mfma_f32_16x16x32_bf16(aA[m][1], bLo[n][1], acc[m][n], 0, 0, 0);
            }
        __builtin_amdgcn_s_setprio(0);
        __builtin_amdgcn_s_barrier();

        // ---- phase 1: read B-h1 (n2..3); stage (t+2,A,h0) ----
#pragma unroll
        for (int n = 0; n < 2; ++n) {
            const int r = bb + ((4 * (n + 2) + wn) << 10) + arow;
            bHi[n][0] = *(const bf16x8_t*)&lds[r + c0];
            bHi[n][1] = *(const bf16x8_t*)&lds[r + c1];
        }
        if (t + 2 < NT) stage_half(t + 2, 0, 0);
        __builtin_amdgcn_s_barrier();
        asm volatile("s_waitcnt lgkmcnt(0)" ::: "memory");
        __builtin_amdgcn_sched_barrier(0);
        __builtin_amdgcn_s_setprio(1);
#pragma unroll
        for (int m = 0; m < 4; ++m)
#pragma unroll
            for (int n = 0; n < 2; ++n) {
                acc[m][2 + n] = __builtin_amdgcn_mfma_f32_16x16x32_bf16(aA[m][0], bHi[n][0], acc[m][2 + n], 0, 0, 0);
                acc[m][2 + n] = __builtin_amdgcn_mfma_f32_16x16x32_bf16(aA[m][1], bHi[n][1], acc[m][2 + n], 0, 0, 0);
            }
        __builtin_amdgcn_s_setprio(0);
        __builtin_amdgcn_s_barrier();

        // ---- phase 2: read A-h1 (m4..7, reuses aA regs); stage (t+2,B,h0) ----
#pragma unroll
        for (int m = 0; m < 4; ++m) {
            const int r = ab + ((2 * (m + 4) + wm) << 10) + arow;
            aA[m][0] = *(const bf16x8_t*)&lds[r + c0];
            aA[m][1] = *(const bf16x8_t*)&lds[r + c1];
        }
        if (t + 2 < NT) stage_half(t + 2, 1, 0);
        __builtin_amdgcn_s_barrier();
        asm volatile("s_waitcnt lgkmcnt(0)" ::: "memory");
        __builtin_amdgcn_sched_barrier(0);
        __builtin_amdgcn_s_setprio(1);
#pragma unroll
        for (int m = 0; m < 4; ++m)
#pragma unroll
            for (int n = 0; n < 2; ++n) {
                acc[4 + m][2 + n] = __builtin_amdgcn_mfma_f32_16x16x32_bf16(aA[m][0], bHi[n][0], acc[4 + m][2 + n], 0, 0, 0);
                acc[4 + m][2 + n] = __builtin_amdgcn_mfma_f32_16x16x32_bf16(aA[m][1], bHi[n][1], acc[4 + m][2 + n], 0, 0, 0);
            }
        __builtin_amdgcn_s_setprio(0);
        __builtin_amdgcn_s_barrier();

        // ---- phase 3: no reads; stage (t+2,A,h1); boundary vmcnt ----
        if (t + 2 < NT) stage_half(t + 2, 0, 1);
        __builtin_amdgcn_s_barrier();
        asm volatile("s_waitcnt lgkmcnt(0)" ::: "memory");
        __builtin_amdgcn_sched_barrier(0);
        __builtin_amdgcn_s_setprio(1);
#pragma unroll
        for (int m = 0; m < 4; ++m)
#pragma unroll
            for (int n = 0; n < 2; ++n) {
                acc[4 + m][n] = __builtin_amdgcn_mfma_f32_16x16x32_bf16(aA[m][0], bLo[n][0], acc[4 + m][n], 0, 0, 0);
                acc[4 + m][n] = __builtin_amdgcn_mfma_f32_16x16x32_bf16(aA[m][1], bLo[n][1], acc[4 + m][n], 0, 0, 0);
            }
        __builtin_amdgcn_s_setprio(0);
        if (t + 2 < NT)      asm volatile("s_waitcnt vmcnt(6)" ::: "memory");
        else if (t + 1 < NT) asm volatile("s_waitcnt vmcnt(0)" ::: "memory");
        __builtin_amdgcn_s_barrier();
    }

    // ---- epilogue: C write ----
#pragma unroll
    for (int m = 0; m < 8; ++m) {
        const int rbase = m0 + (2 * m + wm) * 16 + quad * 4;
#pragma unroll
        for (int n = 0; n < 4; ++n) {
            const int col = n0 + (4 * n + wn) * 16 + ml;
#pragma unroll
            for (int r = 0; r < 4; ++r) {
                const float v = acc[m][n][r];
                if constexpr (sizeof(OutT) == 2) {
                    ((unsigned short*)C)[(size_t)(rbase + r) * ldc + col] = f2b(v);
                } else {
                    ((float*)C)[(size_t)(rbase + r) * ldc + col] = v;
                }
            }
        }
    }
}

// ---------------------------------------------------------------------------
// 128x256-tile variant (fp32 out) for the output projection: grid 4x64 = 256
// blocks = full chip. 512 threads = 8 waves (2M x 4N), per-wave 64x64 out.
// LDS 96 KiB. 2 phases/K-tile; boundary vmcnt(4).
// ---------------------------------------------------------------------------
__global__ __launch_bounds__(512, 2)
void gemm_bf16_128x256(const unsigned short* __restrict__ A, const unsigned short* __restrict__ Bw,
                       float* __restrict__ C, int K, int lda, int ldb, int ldc)
{
    __shared__ unsigned short lds[49152];   // 96 KiB
    const int tid  = threadIdx.x;
    const int wid  = tid >> 6, lane = tid & 63;
    const int wm   = wid >> 2, wn = wid & 3;
    const int ml   = lane & 15, quad = lane >> 4;
    const int nwg = gridDim.x * gridDim.y;
    const int lin = blockIdx.y * gridDim.x + blockIdx.x;
    const int swz_id = (lin & 7) * (nwg >> 3) + (lin >> 3);
    const int m0   = (swz_id / gridDim.x) * 128, n0 = (swz_id % gridDim.x) * 256;
    const int NT   = K >> 6;

    const int srow  = tid >> 3;
    const int scol  = ((tid & 7) ^ (srow & 7)) << 3;
    const int wbase = wid << 9;

    auto stage_unit = [&](int t, int isB, int u) {
        const unsigned short* g0 = isB ? Bw : A;
        const int ld = isB ? ldb : lda;
        const int rb = (isB ? n0 : m0) + u * 64 + srow;
        const int k0 = t << 6;
        unsigned short* lb = lds + (isB ? 16384 : 0) + ((t & 1) << (isB ? 14 : 13))
                             + (u << 12) + wbase;
        const unsigned short* g = g0 + (size_t)rb * ld + k0 + scol;
        __builtin_amdgcn_global_load_lds((const __attribute__((address_space(1))) void*)g,
                                         (__attribute__((address_space(3))) void*)lb, 16, 0, 0);
    };

    f32x4_t acc[4][4];
#pragma unroll
    for (int i = 0; i < 4; ++i)
#pragma unroll
        for (int j = 0; j < 4; ++j) acc[i][j] = (f32x4_t){0.f, 0.f, 0.f, 0.f};

    stage_unit(0, 0, 0); stage_unit(0, 0, 1);
    stage_unit(0, 1, 0); stage_unit(0, 1, 1); stage_unit(0, 1, 2); stage_unit(0, 1, 3);
    stage_unit(1, 0, 0); stage_unit(1, 0, 1);
    stage_unit(1, 1, 0); stage_unit(1, 1, 1);
    asm volatile("s_waitcnt vmcnt(4)" ::: "memory");
    __builtin_amdgcn_s_barrier();

    const int swz  = (ml & 7) << 3;
    const int c0   = (quad << 3) ^ swz;
    const int c1   = (32 + (quad << 3)) ^ swz;
    const int arow = ml << 6;

    bf16x8_t aA[4][2], bF[2][2];

    for (int t = 0; t < NT; ++t) {
        const int ab = (t & 1) << 13;
        const int bb = 16384 + ((t & 1) << 14);

        // ---- phase 0: read A (m0..3) + B-lo (n0..1); stage (t+1,B,u2,u3) ----
#pragma unroll
        for (int m = 0; m < 4; ++m) {
            const int r = ab + ((2 * m + wm) << 10) + arow;
            aA[m][0] = *(const bf16x8_t*)&lds[r + c0];
            aA[m][1] = *(const bf16x8_t*)&lds[r + c1];
        }
#pragma unroll
        for (int n = 0; n < 2; ++n) {
            const int r = bb + ((4 * n + wn) << 10) + arow;
            bF[n][0] = *(const bf16x8_t*)&lds[r + c0];
            bF[n][1] = *(const bf16x8_t*)&lds[r + c1];
        }
        if (t + 1 < NT) { stage_unit(t + 1, 1, 2); stage_unit(t + 1, 1, 3); }
        __builtin_amdgcn_s_barrier();
        asm volatile("s_waitcnt lgkmcnt(0)" ::: "memory");
        __builtin_amdgcn_sched_barrier(0);
        __builtin_amdgcn_s_setprio(1);
#pragma unroll
        for (int m = 0; m < 4; ++m)
#pragma unroll
            for (int n = 0; n < 2; ++n) {
                acc[m][n] = __builtin_amdgcn_mfma_f32_16x16x32_bf16(aA[m][0], bF[n][0], acc[m][n], 0, 0, 0);
                acc[m][n] = __builtin_amdgcn_mfma_f32_16x16x32_bf16(aA[m][1], bF[n][1], acc[m][n], 0, 0, 0);
            }
        __builtin_amdgcn_s_setprio(0);
        __builtin_amdgcn_s_barrier();

        // ---- phase 1: read B-hi (n2..3); stage (t+2,A,0,1)+(t+2,B,0,1) ----
#pragma unroll
        for (int n = 0; n < 2; ++n) {
            const int r = bb + ((4 * (n + 2) + wn) << 10) + arow;
            bF[n][0] = *(const bf16x8_t*)&lds[r + c0];
            bF[n][1] = *(const bf16x8_t*)&lds[r + c1];
        }
        if (t + 2 < NT) {
            stage_unit(t + 2, 0, 0); stage_unit(t + 2, 0, 1);
            stage_unit(t + 2, 1, 0); stage_unit(t + 2, 1, 1);
        }
        __builtin_amdgcn_s_barrier();
        asm volatile("s_waitcnt lgkmcnt(0)" ::: "memory");
        __builtin_amdgcn_sched_barrier(0);
        __builtin_amdgcn_s_setprio(1);
#pragma unroll
        for (int m = 0; m < 4; ++m)
#pragma unroll
            for (int n = 0; n < 2; ++n) {
                acc[m][2 + n] = __builtin_amdgcn_mfma_f32_16x16x32_bf16(aA[m][0], bF[n][0], acc[m][2 + n], 0, 0, 0);
                acc[m][2 + n] = __builtin_amdgcn_mfma_f32_16x16x32_bf16(aA[m][1], bF[n][1], acc[m][2 + n], 0, 0, 0);
            }
        __builtin_amdgcn_s_setprio(0);
        if (t + 2 < NT)      asm volatile("s_waitcnt vmcnt(4)" ::: "memory");
        else if (t + 1 < NT) asm volatile("s_waitcnt vmcnt(0)" ::: "memory");
        __builtin_amdgcn_s_barrier();
    }

    // ---- epilogue: fp32 C write ----
#pragma unroll
    for (int m = 0; m < 4; ++m) {
        const int rbase = m0 + (2 * m + wm) * 16 + quad * 4;
#pragma unroll
        for (int n = 0; n < 4; ++n) {
            const int col = n0 + (4 * n + wn) * 16 + ml;
#pragma unroll
            for (int r = 0; r < 4; ++r)
                C[(size_t)(rbase + r) * ldc + col] = acc[m][n][r];
        }
    }
}

// ---------------------------------------------------------------------------
// state_kernel: per (bh,c) computes S_c = Kf^T @ V_ext (MFMA), stored in the
// TILED layout: slab[dtile 0..17][e 0..64][dlocal 0..15], d = dtile*16+dlocal.
// e=64 is the z (ones) column; e=65..79 zeros are NOT stored (65-row slab).
// Feature order d: [1][q/2 x16][0 x7][qxq/(4sqrt2) x256][0 x8].
// ---------------------------------------------------------------------------
__global__ __launch_bounds__(256)
void state_kernel(const unsigned short* __restrict__ qkv, unsigned short* __restrict__ STg)
{
    __shared__ unsigned short KT[16 * 136];   // K transposed [f][j], padded
    __shared__ unsigned short VT[80 * 136];   // V_ext transposed [e][j], padded

    const int x = blockIdx.x;
    const int c = x & 15, bh = x >> 4;
    const int b = bh >> 4, h = bh & 15;
    const int tid = threadIdx.x;
    const int wave = tid >> 6, lane = tid & 63;
    const int ml = lane & 15, kg8 = (lane >> 4) * 8;
    const int quad4 = (lane >> 4) * 4;
    const size_t rowbase = (size_t)(b * LL + c * CHUNK);
    const size_t Sbase = (size_t)x * SROW;

    {
        const int row = tid >> 1, half = tid & 1;
        uint4 kv = *(const uint4*)(qkv + (rowbase + row) * QKVLD + 256 + h * 16 + half * 8);
        const unsigned short* kp = (const unsigned short*)&kv;
#pragma unroll
        for (int i = 0; i < 8; ++i) KT[(half * 8 + i) * 136 + row] = kp[i];
#pragma unroll
        for (int cc = 0; cc < 4; ++cc) {
            uint4 vv = *(const uint4*)(qkv + (rowbase + row) * QKVLD + 512 + h * 64 + half * 32 + cc * 8);
            const unsigned short* vp = (const unsigned short*)&vv;
#pragma unroll
            for (int i = 0; i < 8; ++i) VT[(half * 32 + cc * 8 + i) * 136 + row] = vp[i];
        }
        if (half == 0) {
            VT[64 * 136 + row] = 0x3F80;   // ones column
        } else {
#pragma unroll
            for (int e = 65; e < 80; ++e) VT[e * 136 + row] = 0;
        }
    }
    __syncthreads();

    bf16x8_t bfr[5][4];
#pragma unroll
    for (int nt = 0; nt < 5; ++nt)
#pragma unroll
        for (int ks = 0; ks < 4; ++ks)
            bfr[nt][ks] = *(const bf16x8_t*)&VT[(nt * 16 + ml) * 136 + ks * 32 + kg8];

    for (int mt = wave; mt < 18; mt += 4) {
        const int d = mt * 16 + ml;
        bf16x8_t af[4];
#pragma unroll
        for (int ks = 0; ks < 4; ++ks) {
            const int jb = ks * 32 + kg8;
            unsigned short o[8];
            if (d >= 24 && d < 280) {
                const int e = d - 24, a = e >> 4, bq = e & 15;
                bf16x8_t ka = *(const bf16x8_t*)&KT[a  * 136 + jb];
                bf16x8_t kb = *(const bf16x8_t*)&KT[bq * 136 + jb];
#pragma unroll
                for (int j = 0; j < 8; ++j)
                    o[j] = f2b(b2f((unsigned short)ka[j]) * b2f((unsigned short)kb[j]) * INV_R2RD);
            } else if (d == 0) {
#pragma unroll
                for (int j = 0; j < 8; ++j) o[j] = 0x3F80;
            } else if (d <= 16) {
                bf16x8_t kx = *(const bf16x8_t*)&KT[(d - 1) * 136 + jb];
#pragma unroll
                for (int j = 0; j < 8; ++j) o[j] = f2b(b2f((unsigned short)kx[j]) * 0.5f);
            } else {
#pragma unroll
                for (int j = 0; j < 8; ++j) o[j] = 0;
            }
            af[ks] = *(const bf16x8_t*)o;
        }
        f32x4_t acc[5];
#pragma unroll
        for (int nt = 0; nt < 5; ++nt) acc[nt] = (f32x4_t){0.f, 0.f, 0.f, 0.f};
        __builtin_amdgcn_s_setprio(1);
#pragma unroll
        for (int nt = 0; nt < 5; ++nt)
#pragma unroll
            for (int ks = 0; ks < 4; ++ks)
                acc[nt] = __builtin_amdgcn_mfma_f32_16x16x32_bf16(af[ks], bfr[nt][ks], acc[nt], 0, 0, 0);
        __builtin_amdgcn_s_setprio(0);
        // tiled store: slab[mt][e][dlocal = quad4 + r]; nt=4 -> only z row e=64
#pragma unroll
        for (int nt = 0; nt < 5; ++nt) {
            ushort4 pk;
            pk.x = f2b(acc[nt][0]); pk.y = f2b(acc[nt][1]);
            pk.z = f2b(acc[nt][2]); pk.w = f2b(acc[nt][3]);
            if (nt < 4) {
                *(ushort4*)(STg + Sbase + (size_t)mt * 1040 + (nt * 16 + ml) * 16 + quad4) = pk;
            } else if (ml == 0) {
                *(ushort4*)(STg + Sbase + (size_t)mt * 1040 + 1024 + quad4) = pk;
            }
        }
    }
}

// ---------------------------------------------------------------------------
// scan: exclusive prefix over the 16 chunks, elementwise, uint4 per thread.
// All 16 chunk loads issued up-front (one HBM round-trip), then acc+store.
// ---------------------------------------------------------------------------
__global__ __launch_bounds__(256)
void scan_S(unsigned short* __restrict__ STg) {
    const int bh  = blockIdx.y;
    const int idx = blockIdx.x * 256 + threadIdx.x;   // uint4 index, 0..2339
    if (idx >= SROW / 8) return;
    const size_t base = (size_t)bh * NCHUNK * SROW + (size_t)idx * 8;
    uint4 v[NCHUNK];
#pragma unroll
    for (int c = 0; c < NCHUNK; ++c)
        v[c] = *(const uint4*)(STg + base + (size_t)c * SROW);
    float acc[8] = {};
#pragma unroll
    for (int c = 0; c < NCHUNK; ++c) {
        const unsigned short* vp = (const unsigned short*)&v[c];
        uint4 o;
        unsigned short* op = (unsigned short*)&o;
#pragma unroll
        for (int i = 0; i < 8; ++i) { op[i] = f2b(acc[i]); acc[i] += b2f(vp[i]); }
        *(uint4*)(STg + base + (size_t)c * SROW) = o;
    }
}

// ---------------------------------------------------------------------------
// out_kernel: per (bh,c), 256 threads / 4 waves.
// Phase 1: A = poly(Q K^T / 4) masked (MFMA), A staged bf16 in LDS.
// Phase 2a: Y += A @ V_ext (MFMA, VT in LDS).
// Phase 2b: Y += Qf @ S_ext, B-fragments global->VGPR from the tiled ST
//   slab, 3-slot ring, 2-deep prefetch (kq+3 issued after MFMA of kq).
// T14: V-tile global loads issued at kernel TOP into registers (in flight
// through phase 1), ds_written to VT after the barrier.
// Q-scalar for Qf build comes from registers (qA/qB), not LDS: the smem-QS
// buffer is gone; index e0>>4 = 2kq + {-2,-1,-1,0}[quad] (compile-time per
// unrolled kq), lo/hi q-half select is quad-parity (hoisted).
// LDS (ushort): Qpad[128*40]@0 + Kpad[128*40]@5120 (VT[80*136]@0 overlays
// both after phase 1) | A[128*136]@10880.  Total 28288 ushort = 56576 B.
// ---------------------------------------------------------------------------
#define OFF_VT 0
#define OFF_QP 0
#define OFF_KP 5120
#define OFF_A  10880

__global__ __launch_bounds__(256)
void out_kernel(const unsigned short* __restrict__ qkv_ro, const unsigned short* __restrict__ STg,
                unsigned short* __restrict__ qkv_w)
{
    __shared__ unsigned short smem[28288];   // 56576 B

    const int x = blockIdx.x;
    const int c = x & 15, bh = x >> 4;
    const int b = bh >> 4, h = bh & 15;
    const int tid = threadIdx.x;
    const int w = tid >> 6, lane = tid & 63;
    const int ml = lane & 15, quad = lane >> 4, kg8 = quad * 8;
    const size_t rowbase = (size_t)(b * LL + c * CHUNK);
    const size_t Sbase = (size_t)x * SROW;

    // ---- ST slice loader: tiled slab, per-mt stride 1040, per-kq 2080 ----
    const unsigned short* stp = STg + Sbase + (size_t)(quad >> 1) * 1040 + (quad & 1) * 8;
    bf16x8_t stf[3][5];
    auto ldst = [&](int kq, int slot) {
#pragma unroll
        for (int nt = 0; nt < 5; ++nt)
            stf[slot][nt] = *(const bf16x8_t*)(stp + (size_t)kq * 2080 + (nt * 16 + ml) * 16);
    };

    // ---- issue ALL long-latency loads up front (T14) ----
    const int row = tid >> 1, half = tid & 1;
    uint4 qv = *(const uint4*)(qkv_ro + (rowbase + row) * QKVLD + h * 16 + half * 8);
    uint4 kv = *(const uint4*)(qkv_ro + (rowbase + row) * QKVLD + 256 + h * 16 + half * 8);
    uint4 vreg[4];
#pragma unroll
    for (int cc = 0; cc < 4; ++cc)
        vreg[cc] = *(const uint4*)(qkv_ro + (rowbase + row) * QKVLD + 512 + h * 64 + half * 32 + cc * 8);
    ldst(0, 0);
    ldst(1, 1);

    // ---- stage Q (padded) and K (padded) ----
    *(uint4*)&smem[OFF_QP + row * 40 + half * 8] = qv;
    *(uint4*)&smem[OFF_QP + row * 40 + 16 + half * 8] = (uint4){0, 0, 0, 0};
    *(uint4*)&smem[OFF_KP + row * 40 + half * 8] = kv;
    *(uint4*)&smem[OFF_KP + row * 40 + 16 + half * 8] = (uint4){0, 0, 0, 0};
    __syncthreads();

    // ---- phase 1: scores ----
    {
        bf16x8_t q0 = *(const bf16x8_t*)&smem[OFF_QP + (w * 32 + ml) * 40 + kg8];
        bf16x8_t q1 = *(const bf16x8_t*)&smem[OFF_QP + (w * 32 + 16 + ml) * 40 + kg8];
#pragma unroll
        for (int nt = 0; nt < 8; ++nt) {
            bf16x8_t kf = *(const bf16x8_t*)&smem[OFF_KP + (nt * 16 + ml) * 40 + kg8];
            f32x4_t a0 = __builtin_amdgcn_mfma_f32_16x16x32_bf16(q0, kf, (f32x4_t){0,0,0,0}, 0, 0, 0);
            f32x4_t a1 = __builtin_amdgcn_mfma_f32_16x16x32_bf16(q1, kf, (f32x4_t){0,0,0,0}, 0, 0, 0);
            const int j = nt * 16 + ml;
#pragma unroll
            for (int r = 0; r < 4; ++r) {
                int i0 = w * 32 + quad * 4 + r;
                float s0 = a0[r] * 0.25f;
                float v0 = (j <= i0) ? (1.f + s0 + 0.5f * s0 * s0) : 0.f;
                smem[OFF_A + i0 * 136 + j] = f2b(v0);
                int i1 = i0 + 16;
                float s1 = a1[r] * 0.25f;
                float v1 = (j <= i1) ? (1.f + s1 + 0.5f * s1 * s1) : 0.f;
                smem[OFF_A + i1 * 136 + j] = f2b(v1);
            }
        }
    }
    // q f32 registers for Qf build (from QP, still alive before VT overlay)
    const int r0 = w * 32 + ml, r1 = r0 + 16;
    float qA[16], qB[16];
    {
        bf16x8_t t0 = *(const bf16x8_t*)&smem[OFF_QP + r0 * 40];
        bf16x8_t t1 = *(const bf16x8_t*)&smem[OFF_QP + r0 * 40 + 8];
        bf16x8_t t2 = *(const bf16x8_t*)&smem[OFF_QP + r1 * 40];
        bf16x8_t t3 = *(const bf16x8_t*)&smem[OFF_QP + r1 * 40 + 8];
#pragma unroll
        for (int i = 0; i < 8; ++i) {
            qA[i] = b2f((unsigned short)t0[i]); qA[8 + i] = b2f((unsigned short)t1[i]);
            qB[i] = b2f((unsigned short)t2[i]); qB[8 + i] = b2f((unsigned short)t3[i]);
        }
    }
    // quad-parity q-half select, loop-invariant over kq (hoisted)
    float qselA[8], qselB[8];
#pragma unroll
    for (int j = 0; j < 8; ++j) {
        qselA[j] = (quad & 1) ? qA[j] : qA[8 + j];
        qselB[j] = (quad & 1) ? qB[j] : qB[8 + j];
    }
    __syncthreads();   // A-writes + Qpad/Kpad reads done before VT overlay

    // ---- write VT (overlays Qpad/Kpad) from the registers loaded at top ----
    {
#pragma unroll
        for (int cc = 0; cc < 4; ++cc) {
            const unsigned short* vp = (const unsigned short*)&vreg[cc];
#pragma unroll
            for (int i = 0; i < 8; ++i) smem[OFF_VT + (half * 32 + cc * 8 + i) * 136 + row] = vp[i];
        }
        if (half == 0) {
            smem[OFF_VT + 64 * 136 + row] = 0x3F80;
        } else {
#pragma unroll
            for (int e = 65; e < 80; ++e) smem[OFF_VT + e * 136 + row] = 0;
        }
    }
    __syncthreads();

    f32x4_t acc[2][5];
#pragma unroll
    for (int mt = 0; mt < 2; ++mt)
#pragma unroll
        for (int nt = 0; nt < 5; ++nt) acc[mt][nt] = (f32x4_t){0.f, 0.f, 0.f, 0.f};

    // prefetch ST slice kq=2 (slot 2) before phase 2a
    ldst(2, 2);

    // ---- phase 2a: A @ V_ext ----
#pragma unroll
    for (int ks = 0; ks < 4; ++ks) {
        bf16x8_t af0 = *(const bf16x8_t*)&smem[OFF_A + (w * 32 + ml) * 136 + ks * 32 + kg8];
        bf16x8_t af1 = *(const bf16x8_t*)&smem[OFF_A + (w * 32 + 16 + ml) * 136 + ks * 32 + kg8];
        __builtin_amdgcn_s_setprio(1);
#pragma unroll
        for (int nt = 0; nt < 5; ++nt) {
            bf16x8_t bv = *(const bf16x8_t*)&smem[OFF_VT + (nt * 16 + ml) * 136 + ks * 32 + kg8];
            acc[0][nt] = __builtin_amdgcn_mfma_f32_16x16x32_bf16(af0, bv, acc[0][nt], 0, 0, 0);
            acc[1][nt] = __builtin_amdgcn_mfma_f32_16x16x32_bf16(af1, bv, acc[1][nt], 0, 0, 0);
        }
        __builtin_amdgcn_s_setprio(0);
    }

    // ---- phase 2b: Qf @ S_ext, 3-slot ring, 2-deep prefetch ----
#pragma unroll
    for (int kq = 0; kq < 9; ++kq) {
        bf16x8_t qf[2];
#pragma unroll
        for (int mt = 0; mt < 2; ++mt) {
            const float* q    = (mt == 0) ? qA : qB;
            const float* qsel = (mt == 0) ? qselA : qselB;
            const int d0 = kq * 32 + kg8;
            unsigned short o[8];
            if (d0 >= 24 && d0 < 280) {
                const int i2 = 2 * kq;
                const float base = (quad == 3) ? q[i2 > 15 ? 15 : i2]
                                 : (quad == 0) ? q[i2 < 2 ? 0 : i2 - 2]
                                               : q[i2 < 1 ? 0 : i2 - 1];
                const float qa = base * INV_R2RD;
#pragma unroll
                for (int j = 0; j < 8; ++j) o[j] = f2b(qa * qsel[j]);
            } else if (d0 == 0) {
                o[0] = 0x3F80;
#pragma unroll
                for (int j = 1; j < 8; ++j) o[j] = f2b(q[j - 1] * 0.5f);
            } else if (d0 == 8) {
#pragma unroll
                for (int j = 0; j < 8; ++j) o[j] = f2b(q[7 + j] * 0.5f);
            } else if (d0 == 16) {
                o[0] = f2b(q[15] * 0.5f);
#pragma unroll
                for (int j = 1; j < 8; ++j) o[j] = 0;
            } else {
#pragma unroll
                for (int j = 0; j < 8; ++j) o[j] = 0;
            }
            qf[mt] = *(const bf16x8_t*)o;
        }
        __builtin_amdgcn_s_setprio(1);
#pragma unroll
        for (int nt = 0; nt < 5; ++nt) {
            acc[0][nt] = __builtin_amdgcn_mfma_f32_16x16x32_bf16(qf[0], stf[kq % 3][nt], acc[0][nt], 0, 0, 0);
            acc[1][nt] = __builtin_amdgcn_mfma_f32_16x16x32_bf16(qf[1], stf[kq % 3][nt], acc[1][nt], 0, 0, 0);
        }
        __builtin_amdgcn_s_setprio(0);
        if (kq + 3 < 9) ldst(kq + 3, kq % 3);
    }

    // ---- epilogue: y = num / (den + eps), den = col 64 (nt=4, ml==0 lanes) ----
#pragma unroll
    for (int mt = 0; mt < 2; ++mt) {
        float den[4];
#pragma unroll
        for (int r = 0; r < 4; ++r) den[r] = __shfl(acc[mt][4][r], lane & 48);
#pragma unroll
        for (int r = 0; r < 4; ++r) {
            const size_t grow = rowbase + w * 32 + mt * 16 + quad * 4 + r;
            const float rc = 1.f / (den[r] + EPS);
#pragma unroll
            for (int nt = 0; nt < 4; ++nt)
                qkv_w[grow * QKVLD + 512 + h * 64 + nt * 16 + ml] = f2b(acc[mt][nt][r] * rc);
        }
    }
}

// ---------------------------------------------------------------------------
extern "C" void kernel_launch(void* const* d_in, const int* in_sizes, int n_in,
                              void* d_out, int out_size, void* d_ws, size_t ws_size,
                              hipStream_t stream)
{
    (void)in_sizes; (void)n_in; (void)out_size; (void)ws_size;
    const float* hs = (const float*)d_in[0];
    const float* Wq = (const float*)d_in[1];
    const float* Wk = (const float*)d_in[2];
    const float* Wv = (const float*)d_in[3];
    const float* Wo = (const float*)d_in[4];
    float* out = (float*)d_out;

    char* ws = (char*)d_ws;
    // S region (64*16*18720*2 = 38.3 MB used, 47.2 MB reserved) at 0; hs_bf
    // (16 MB) aliases its start (dead before state_kernel writes S).
    unsigned short* STg   = (unsigned short*)ws;
    unsigned short* hs_bf = (unsigned short*)ws;
    size_t off = 47185920;
    unsigned short* qkv   = (unsigned short*)(ws + off); off += 25165824;  // 8192x1536
    unsigned short* Wqkv  = (unsigned short*)(ws + off); off += 3145728;   // 1536x1024
    unsigned short* Wo_bf = (unsigned short*)(ws + off); off += 2097152;   // total 77.6 MB

    cast_all<<<10752, 256, 0, stream>>>(hs, Wq, Wk, Wv, Wo, hs_bf, Wqkv, Wo_bf);
    // QKV projection: C[8192,1536] = hs_bf[8192,1024] @ Wqkv^T, 256^2 tiles
    gemm_bf16_8ph<unsigned short><<<dim3(6, 32), 512, 0, stream>>>(hs_bf, Wqkv, qkv,
                                                                   DM, DM, DM, QKVLD);
    state_kernel<<<1024, 256, 0, stream>>>(qkv, STg);
    scan_S<<<dim3(10, 64), 256, 0, stream>>>(STg);
    out_kernel<<<1024, 256, 0, stream>>>(qkv, STg, qkv);   // y in-place over v cols
    // output projection: out[8192,1024] = y[8192,1024] @ Wo^T, 128x256 tiles
    gemm_bf16_128x256<<<dim3(4, 64), 512, 0, stream>>>(qkv + 512, Wo_bf, out,
                                                       DM, QKVLD, DM, DM);
}